// Round 7
// baseline (841.511 us; speedup 1.0000x reference)
//
#include <hip/hip_runtime.h>

typedef unsigned short u16;
typedef __bf16 bf16x8 __attribute__((ext_vector_type(8)));
typedef float f32x4 __attribute__((ext_vector_type(4)));

static __device__ __forceinline__ float bf2f(u16 u) {
    union { unsigned int i; float f; } v; v.i = ((unsigned int)u) << 16; return v.f;
}
static __device__ __forceinline__ u16 f2bf(float f) {
    union { float f; unsigned int i; } v; v.f = f;
    unsigned int b = v.i;
    b += 0x7fffu + ((b >> 16) & 1u);   // RNE
    return (u16)(b >> 16);
}
static __device__ __forceinline__ u16 ldbf(const void* p, size_t i, int isf32) {
    return isf32 ? f2bf(((const float*)p)[i]) : ((const u16*)p)[i];
}
static __device__ __forceinline__ float ldf(const void* p, size_t i, int isf32) {
    return isf32 ? ((const float*)p)[i] : bf2f(((const u16*)p)[i]);
}
// async global->LDS, 16B per lane; lds dest = wave-uniform base + lane*16 (m97/m104)
static __device__ __forceinline__ void glds16(const u16* g, u16* l) {
    __builtin_amdgcn_global_load_lds(
        (const __attribute__((address_space(1))) unsigned int*)g,
        (__attribute__((address_space(3))) unsigned int*)l,
        16, 0, 0);
}
// XCD-chunked bijective remap (T1, m192). Used ONLY for k_gemm8 (verified helpful there;
// hurt k_gemm_t/attn in round 4 -> reverted for those).
static __device__ __forceinline__ int xcd_swz(int lid, int nwg) {
    return ((nwg & 7) == 0) ? ((lid & 7) * (nwg >> 3) + (lid >> 3)) : lid;
}

// ---------------- dtype detector (insurance; inputs measured fp32) ----------------
__global__ __launch_bounds__(256) void k_detect(const u16* __restrict__ xu, int* __restrict__ flag) {
    u16 v = xu[threadIdx.x * 2];
    int e = (v >> 7) & 0xFF;
    int sane = (e >= 87 && e <= 133) ? 1 : 0;
    int total = __syncthreads_count(sane);
    if (threadIdx.x == 0) flag[0] = (total < 192) ? 1 : 0;
}

// ---------------- x -> f32 residual stream ----------------
__global__ __launch_bounds__(256) void k_b2f(const void* __restrict__ in, float* __restrict__ out, int n,
                                             const int* __restrict__ flagp) {
    int isf32 = *flagp;
    int i = blockIdx.x * 256 + threadIdx.x;
    if (i < n) out[i] = ldf(in, i, isf32);
}

// ---------------- external -> bf16 convert ----------------
__global__ __launch_bounds__(256) void k_cvt(const void* __restrict__ in, u16* __restrict__ out, int n,
                                             const int* __restrict__ flagp) {
    int isf32 = *flagp;
    int i = blockIdx.x * 256 + threadIdx.x;
    if (i < n) out[i] = ldbf(in, i, isf32);
}

// ---------------- split-K reduce: X += P (fp32, vectorized) ----------------
__global__ __launch_bounds__(256) void k_addp(float* __restrict__ X, const float* __restrict__ P, int n4) {
    int i = blockIdx.x * 256 + threadIdx.x;
    int stride = gridDim.x * 256;
    for (; i < n4; i += stride) {
        f32x4 a = ((const f32x4*)X)[i];
        f32x4 b = ((const f32x4*)P)[i];
        a[0] += b[0]; a[1] += b[1]; a[2] += b[2]; a[3] += b[3];
        ((f32x4*)X)[i] = a;
    }
}

// ---------------- weight transpose+convert: W[K,N] (ext) -> Wt[N,K] bf16 ----------------
__global__ __launch_bounds__(256) void k_transpose(const void* __restrict__ W, u16* __restrict__ Wt,
                                                   int K, int N, const int* __restrict__ flagp) {
    int isf32 = *flagp;
    __shared__ u16 T[32][33];
    int k0 = blockIdx.x * 32, n0 = blockIdx.y * 32;
    int tid = threadIdx.x;
    int c = tid & 31, rr = tid >> 5;
    #pragma unroll
    for (int j = 0; j < 4; ++j) {
        int k = rr + j * 8;
        T[k][c] = ldbf(W, (size_t)(k0 + k) * N + n0 + c, isf32);
    }
    __syncthreads();
    #pragma unroll
    for (int j = 0; j < 4; ++j) {
        int n = rr + j * 8;
        Wt[(size_t)(n0 + n) * K + k0 + c] = T[c][n];
    }
}

// ---------------- LayerNorm: fp32 in -> bf16 out ----------------
__global__ __launch_bounds__(256) void k_layernorm(const float* __restrict__ X, const void* __restrict__ G,
                                                   const void* __restrict__ Bb, u16* __restrict__ Y, int D,
                                                   const int* __restrict__ flagp) {
    int isf32 = *flagp;
    int row = blockIdx.x;
    const float* xr = X + (size_t)row * D;
    float s = 0.f, s2 = 0.f;
    for (int i = threadIdx.x; i < D; i += 256) { float v = xr[i]; s += v; s2 += v * v; }
    #pragma unroll
    for (int off = 32; off; off >>= 1) { s += __shfl_down(s, off); s2 += __shfl_down(s2, off); }
    __shared__ float rs[4], rs2[4];
    __shared__ float stat[2];
    int w = threadIdx.x >> 6;
    if ((threadIdx.x & 63) == 0) { rs[w] = s; rs2[w] = s2; }
    __syncthreads();
    if (threadIdx.x == 0) {
        float ts = rs[0] + rs[1] + rs[2] + rs[3];
        float ts2 = rs2[0] + rs2[1] + rs2[2] + rs2[3];
        float mu = ts / D;
        float var = ts2 / D - mu * mu;
        stat[0] = mu; stat[1] = rsqrtf(var + 1e-5f);
    }
    __syncthreads();
    float mu = stat[0], rstd = stat[1];
    u16* yr = Y + (size_t)row * D;
    for (int i = threadIdx.x; i < D; i += 256) {
        yr[i] = f2bf((xr[i] - mu) * rstd * ldf(G, i, isf32) + ldf(Bb, i, isf32));
    }
}

// ============ 256x256 GEMM, overlapped 4-phase schedule (T1..T5 + counted-lgkm) ============
// LDS (u16 units): buf d at d*32768; A at +0, B at +16384; half h at +h*8192.
// Swizzle: 16B chunk q of row rr stored at chunk (q ^ (rr&7)) -- linear glds dest,
// inverse-swizzled global source, swizzled ds_read (rule #21).
// NEW (round 7): each phase ISSUES the next phase's ds_reads BEFORE its own MFMA; the
// compiler's auto counted-lgkmcnt (m97 precedent) drains only the older reads -> the
// new reads are serviced by the LDS pipe WHILE the matrix pipe runs. 1 barrier/phase
// (4/tile, was 8). Gray-code (0,0)->(0,1)->(1,1)->(1,0); afA/bf0 of tile t+1 issue
// after ph3's vmcnt(4)+barrier (chip-wide RAW-safe). WAR windows audited: every glds
// stage-write lands >=1 barrier after all waves' lgkm drain of that region.
// Stage schedule: ph0: A1(t+1), ph1: B1(t+1), ph2: A0(t+2), ph3: B0(t+2);
// vmcnt(4) at ph3 only (oldest 8 of 12 = all of tile t+1; never 0 in main loop).
// EPI 0: plain bf16 store. EPI 1: GEGLU (B-rows remapped; pairing within-thread).
template <int EPI>
__global__ __launch_bounds__(512, 2) void k_gemm8(const u16* __restrict__ A, const u16* __restrict__ Bt,
                                                  void* __restrict__ Cout, const void* __restrict__ bias,
                                                  int M, int N, int K, const int* __restrict__ flagp) {
    __shared__ __align__(16) u16 sm[65536];   // 128 KiB static
    const int tid = threadIdx.x;
    const int w = tid >> 6;
    const int lane = tid & 63;
    const int quad = lane >> 4, r = lane & 15;
    const int wm = w >> 2, wn = w & 3;          // 2 x 4 wave grid
    const int lid = blockIdx.x + blockIdx.y * gridDim.x;
    const int nid = xcd_swz(lid, gridDim.x * gridDim.y);
    const int row0 = (nid % gridDim.x) * 256;
    const int col0 = (nid / gridDim.x) * 256;
    const int NT = K >> 6;

    // staging geometry: per call j, chunk c = w*128 + j*64 + lane
    const u16* aP[2][2];
    const u16* bP[2][2];
    #pragma unroll
    for (int j = 0; j < 2; ++j) {
        int c = tid + w * 64 + j * 64;          // = w*128 + j*64 + lane
        int rj = c >> 3;                        // row within half (0..127)
        int qe = (c & 7) ^ (rj & 7);            // inverse-swizzled global chunk
        #pragma unroll
        for (int h = 0; h < 2; ++h) {
            int gr = h * 128 + rj;
            aP[h][j] = A + (size_t)(row0 + gr) * K + qe * 8;
            int n = col0 + gr;
            int m = (EPI == 1) ? (((n >> 4) & 1) * 5120 + (n >> 5) * 16 + (n & 15)) : n;
            bP[h][j] = Bt + (size_t)m * K + qe * 8;
        }
    }
    auto stageA = [&](int h, int t) {
        u16* base = sm + (t & 1) * 32768 + h * 8192 + w * 1024;
        glds16(aP[h][0] + t * 64, base);
        glds16(aP[h][1] + t * 64, base + 512);
    };
    auto stageB = [&](int h, int t) {
        u16* base = sm + (t & 1) * 32768 + 16384 + h * 8192 + w * 1024;
        glds16(bP[h][0] + t * 64, base);
        glds16(bP[h][1] + t * 64, base + 512);
    };

    f32x4 acc[2][2][4][2] = {};
    const int xq = r & 7;
    bf16x8 afA[4][2], afB[4][2], bf0[2][2], bf1[2][2];

    auto readA = [&](bf16x8 (&dst)[4][2], int Ab, int half) {
        #pragma unroll
        for (int i = 0; i < 4; ++i) {
            int ar = half * 128 + wm * 64 + i * 16 + r;
            #pragma unroll
            for (int ks = 0; ks < 2; ++ks)
                dst[i][ks] = *(const bf16x8*)(sm + Ab + ar * 64 + (((ks * 4 + quad) ^ xq) * 8));
        }
    };
    auto readB = [&](bf16x8 (&dst)[2][2], int Bb, int half) {
        #pragma unroll
        for (int g = 0; g < 2; ++g) {
            int br = half * 128 + wn * 32 + g * 16 + r;
            #pragma unroll
            for (int ks = 0; ks < 2; ++ks)
                dst[g][ks] = *(const bf16x8*)(sm + Bb + br * 64 + (((ks * 4 + quad) ^ xq) * 8));
        }
    };
    auto domfma = [&](int qm, int qn, bf16x8 (&a)[4][2], bf16x8 (&b)[2][2]) {
        #pragma unroll
        for (int ks = 0; ks < 2; ++ks)
            #pragma unroll
            for (int i = 0; i < 4; ++i)
                #pragma unroll
                for (int g = 0; g < 2; ++g)
                    acc[qm][qn][i][g] = __builtin_amdgcn_mfma_f32_16x16x32_bf16(
                        a[i][ks], b[g][ks], acc[qm][qn][i][g], 0, 0, 0);
    };

    // prologue: tile 0 complete + halves0 of tile 1; vmcnt(4) -> tile 0 landed
    stageA(0, 0); stageB(0, 0); stageA(1, 0); stageB(1, 0);
    if (NT > 1) {
        stageA(0, 1); stageB(0, 1);
        asm volatile("s_waitcnt vmcnt(4)" ::: "memory");
    } else {
        asm volatile("s_waitcnt vmcnt(0)" ::: "memory");
    }
    __builtin_amdgcn_s_barrier();
    // initial frags of tile 0
    readA(afA, 0, 0);
    readB(bf0, 16384, 0);

    for (int t = 0; t < NT; ++t) {
        const int Ab = (t & 1) * 32768;
        const int Bb = Ab + 16384;
        const int Abn = ((t + 1) & 1) * 32768;
        // ---- ph0: MFMA(afA,bf0); prefetch bf1 under it ----
        readB(bf1, Bb, 1);
        __builtin_amdgcn_sched_barrier(0);     // pin read issuance before MFMA
        __builtin_amdgcn_s_setprio(1);
        domfma(0, 0, afA, bf0);
        __builtin_amdgcn_s_setprio(0);
        if (t + 1 < NT) stageA(1, t + 1);
        __builtin_amdgcn_s_barrier();
        // ---- ph1: MFMA(afA,bf1); prefetch afB under it ----
        readA(afB, Ab, 1);
        __builtin_amdgcn_sched_barrier(0);
        __builtin_amdgcn_s_setprio(1);
        domfma(0, 1, afA, bf1);
        __builtin_amdgcn_s_setprio(0);
        if (t + 1 < NT) stageB(1, t + 1);
        __builtin_amdgcn_s_barrier();
        // ---- ph2: MFMA(afB,bf1) (no new reads) ----
        __builtin_amdgcn_s_setprio(1);
        domfma(1, 1, afB, bf1);
        __builtin_amdgcn_s_setprio(0);
        if (t + 2 < NT) stageA(0, t + 2);
        __builtin_amdgcn_s_barrier();
        // ---- ph3: MFMA(afB,bf0); then vmcnt-gate + next-tile frag issue ----
        __builtin_amdgcn_s_setprio(1);
        domfma(1, 0, afB, bf0);
        __builtin_amdgcn_s_setprio(0);
        if (t + 2 < NT) stageB(0, t + 2);
        if (t + 2 < NT) asm volatile("s_waitcnt vmcnt(4)" ::: "memory");
        else            asm volatile("s_waitcnt vmcnt(0)" ::: "memory");
        __builtin_amdgcn_s_barrier();
        if (t + 1 < NT) {                       // tile t+1 landed chip-wide; issue its frags
            readA(afA, Abn, 0);
            readB(bf0, Abn + 16384, 0);
        }
    }

    if (EPI == 0) {
        u16* C = (u16*)Cout;
        #pragma unroll
        for (int qm = 0; qm < 2; ++qm) {
            #pragma unroll
            for (int qn = 0; qn < 2; ++qn) {
                #pragma unroll
                for (int i = 0; i < 4; ++i) {
                    int grow = row0 + qm * 128 + wm * 64 + i * 16 + quad * 4;
                    #pragma unroll
                    for (int g = 0; g < 2; ++g) {
                        int gcol = col0 + qn * 128 + wn * 32 + g * 16 + r;
                        #pragma unroll
                        for (int t4 = 0; t4 < 4; ++t4)
                            C[(size_t)(grow + t4) * N + gcol] = f2bf(acc[qm][qn][i][g][t4]);
                    }
                }
            }
        }
    } else {
        const int isf32 = *flagp;
        u16* C = (u16*)Cout;  // [M][5120]
        #pragma unroll
        for (int qm = 0; qm < 2; ++qm) {
            #pragma unroll
            for (int qn = 0; qn < 2; ++qn) {
                int ncb = col0 + qn * 128 + wn * 32;
                int oc = (ncb >> 1) + r;
                float bva = ldf(bias, oc, isf32);
                float bvu = ldf(bias, 5120 + oc, isf32);
                #pragma unroll
                for (int i = 0; i < 4; ++i) {
                    int grow = row0 + qm * 128 + wm * 64 + i * 16 + quad * 4;
                    #pragma unroll
                    for (int t4 = 0; t4 < 4; ++t4) {
                        float a = acc[qm][qn][i][0][t4] + bva;
                        float u = acc[qm][qn][i][1][t4] + bvu;
                        float z2 = 1.5957691216f * (u + 0.044715f * u * u * u);
                        float gl = u * __builtin_amdgcn_rcpf(1.f + __expf(-z2));
                        C[(size_t)(grow + t4) * 5120 + oc] = f2bf(a * gl);
                    }
                }
            }
        }
    }
}

// ============ FAST PATH: 128x128 tile GEMM via global_load_lds, xor-swizzled LDS ============
// EPI: 0 = bf16 store; 2 = xres += acc + bias (fp32). Split-K (gridDim.z==2):
// kz=0 -> xres += acc + bias (non-atomic, each element owned by one block);
// kz=1 -> plain fp32 store of acc into partial buffer (Cout); k_addp folds it in after.
template <int EPI>
__global__ __launch_bounds__(256) void k_gemm_t(const u16* __restrict__ A, const u16* __restrict__ Bt,
                                                void* __restrict__ Cout, float* __restrict__ Rf,
                                                const void* __restrict__ bias,
                                                int M, int N, int K, const int* __restrict__ flagp) {
    int isf32 = *flagp;
    __shared__ __align__(16) u16 As[4096];
    __shared__ __align__(16) u16 Bs[4096];
    int tid = threadIdx.x;
    int row0 = blockIdx.x * 128, col0 = blockIdx.y * 128;
    int S = gridDim.z, kz = blockIdx.z;
    int kseg = K / S;
    int kb = kz * kseg, ke = kb + kseg;
    int wave = tid >> 6, lane = tid & 63;
    int wm = (wave >> 1) * 64, wn = (wave & 1) * 64;
    int quad = lane >> 4, r = lane & 15;
    int c0 = wave * 64 + lane, c1 = 256 + c0;
    int ar0 = c0 >> 2, aq0 = (c0 & 3) ^ ((ar0 >> 1) & 3);
    int ar1 = c1 >> 2, aq1 = (c1 & 3) ^ ((ar1 >> 1) & 3);
    const u16* Ag0 = A + (size_t)min(row0 + ar0, M - 1) * K + aq0 * 8;
    const u16* Ag1 = A + (size_t)min(row0 + ar1, M - 1) * K + aq1 * 8;
    const u16* Bg0 = Bt + (size_t)(col0 + ar0) * K + aq0 * 8;
    const u16* Bg1 = Bt + (size_t)(col0 + ar1) * K + aq1 * 8;
    u16* lA0 = As + wave * 512;
    u16* lA1 = As + 2048 + wave * 512;
    u16* lB0 = Bs + wave * 512;
    u16* lB1 = Bs + 2048 + wave * 512;
    f32x4 acc[4][4] = {};
    for (int k0 = kb; k0 < ke; k0 += 32) {
        __syncthreads();
        glds16(Ag0 + k0, lA0);
        glds16(Ag1 + k0, lA1);
        glds16(Bg0 + k0, lB0);
        glds16(Bg1 + k0, lB1);
        __syncthreads();
        bf16x8 af[4], bfv[4];
        #pragma unroll
        for (int i = 0; i < 4; ++i) {
            int row = wm + i * 16 + r;
            af[i] = *(const bf16x8*)(As + (row * 4 + (quad ^ ((row >> 1) & 3))) * 8);
        }
        #pragma unroll
        for (int g = 0; g < 4; ++g) {
            int row = wn + g * 16 + r;
            bfv[g] = *(const bf16x8*)(Bs + (row * 4 + (quad ^ ((row >> 1) & 3))) * 8);
        }
        #pragma unroll
        for (int i = 0; i < 4; ++i)
            #pragma unroll
            for (int g = 0; g < 4; ++g)
                acc[i][g] = __builtin_amdgcn_mfma_f32_16x16x32_bf16(af[i], bfv[g], acc[i][g], 0, 0, 0);
    }
    #pragma unroll
    for (int i = 0; i < 4; ++i) {
        int grow = row0 + wm + i * 16 + quad * 4;
        if (grow >= M) continue;
        #pragma unroll
        for (int g = 0; g < 4; ++g) {
            int gcol = col0 + wn + g * 16 + r;
            float bv = (EPI == 2 && kz == 0) ? ldf(bias, gcol, isf32) : 0.f;
            #pragma unroll
            for (int t = 0; t < 4; ++t) {
                float v = acc[i][g][t];
                size_t off = (size_t)(grow + t) * N + gcol;
                if (EPI == 0) {
                    ((u16*)Cout)[off] = f2bf(v);
                } else {
                    if (kz == 0) Rf[off] += v + bv;          // sole owner of this element in z=0
                    else         ((float*)Cout)[off] = v;    // partial; folded in by k_addp
                }
            }
        }
    }
}

// ============ FAST PATH: GEGLU ff1 via global_load_lds; Nout=5120 (fallback for gemm8) ====
__global__ __launch_bounds__(256) void k_geglu_t(const u16* __restrict__ A, const u16* __restrict__ Bt,
                                                 const void* __restrict__ bias, u16* __restrict__ Out,
                                                 int M, int K, const int* __restrict__ flagp) {
    const int Nout = 5120;
    int isf32 = *flagp;
    __shared__ __align__(16) u16 As[4096];
    __shared__ __align__(16) u16 Bs[4096];
    int tid = threadIdx.x;
    int row0 = blockIdx.x * 128, col0 = blockIdx.y * 64;
    int wave = tid >> 6, lane = tid & 63;
    int quad = lane >> 4, r = lane & 15;
    int c0 = wave * 64 + lane, c1 = 256 + c0;
    int ar0 = c0 >> 2, aq0 = (c0 & 3) ^ ((ar0 >> 1) & 3);
    int ar1 = c1 >> 2, aq1 = (c1 & 3) ^ ((ar1 >> 1) & 3);
    const u16* Ag0 = A + (size_t)min(row0 + ar0, M - 1) * K + aq0 * 8;
    const u16* Ag1 = A + (size_t)min(row0 + ar1, M - 1) * K + aq1 * 8;
    const u16* Bg0 = Bt + (size_t)((ar0 >> 6) * Nout + col0 + (ar0 & 63)) * K + aq0 * 8;
    const u16* Bg1 = Bt + (size_t)((ar1 >> 6) * Nout + col0 + (ar1 & 63)) * K + aq1 * 8;
    u16* lA0 = As + wave * 512;
    u16* lA1 = As + 2048 + wave * 512;
    u16* lB0 = Bs + wave * 512;
    u16* lB1 = Bs + 2048 + wave * 512;
    f32x4 acc[2][2][4] = {};
    for (int k0 = 0; k0 < K; k0 += 32) {
        __syncthreads();
        glds16(Ag0 + k0, lA0);
        glds16(Ag1 + k0, lA1);
        glds16(Bg0 + k0, lB0);
        glds16(Bg1 + k0, lB1);
        __syncthreads();
        bf16x8 af[2], bv[2][4];
        #pragma unroll
        for (int i = 0; i < 2; ++i) {
            int row = wave * 32 + i * 16 + r;
            af[i] = *(const bf16x8*)(As + (row * 4 + (quad ^ ((row >> 1) & 3))) * 8);
        }
        #pragma unroll
        for (int p = 0; p < 2; ++p)
            #pragma unroll
            for (int g = 0; g < 4; ++g) {
                int row = p * 64 + g * 16 + r;
                bv[p][g] = *(const bf16x8*)(Bs + (row * 4 + (quad ^ ((row >> 1) & 3))) * 8);
            }
        #pragma unroll
        for (int p = 0; p < 2; ++p)
            #pragma unroll
            for (int i = 0; i < 2; ++i)
                #pragma unroll
                for (int g = 0; g < 4; ++g)
                    acc[p][i][g] = __builtin_amdgcn_mfma_f32_16x16x32_bf16(af[i], bv[p][g], acc[p][i][g], 0, 0, 0);
    }
    #pragma unroll
    for (int i = 0; i < 2; ++i) {
        int grow = row0 + wave * 32 + i * 16 + quad * 4;
        #pragma unroll
        for (int g = 0; g < 4; ++g) {
            int gcol = col0 + g * 16 + r;
            float bva = ldf(bias, gcol, isf32);
            float bvu = ldf(bias, Nout + gcol, isf32);
            #pragma unroll
            for (int t = 0; t < 4; ++t) {
                float a = acc[0][i][g][t] + bva;
                float u = acc[1][i][g][t] + bvu;
                float z2 = 1.5957691216f * (u + 0.044715f * u * u * u);
                float gl = u * __builtin_amdgcn_rcpf(1.f + __expf(-z2));
                Out[(size_t)(grow + t) * Nout + gcol] = f2bf(a * gl);
            }
        }
    }
}

// ============ FALLBACK: round-4 64x64 GEMM (known-good) ============
template <int EPI, bool AEXT>
__global__ __launch_bounds__(256) void k_gemm(const void* __restrict__ A, const void* __restrict__ B,
                                              void* __restrict__ Cout, float* __restrict__ Rf,
                                              const void* __restrict__ bias,
                                              int M, int N, int K, const int* __restrict__ flagp) {
    int isf32 = *flagp;
    __shared__ u16 As[64][40];
    __shared__ u16 Bs[64][40];
    int tid = threadIdx.x;
    int row0 = blockIdx.x * 64, col0 = blockIdx.y * 64;
    int wave = tid >> 6, lane = tid & 63;
    int wm = (wave >> 1) * 32, wn = (wave & 1) * 32;
    int quad = lane >> 4, r = lane & 15;
    int arow = tid >> 2, akk = (tid & 3) * 8;
    int bnl = tid & 63, bkk = (tid >> 6) * 8;
    int garow = row0 + arow;
    f32x4 acc[2][2] = {};
    for (int k0 = 0; k0 < K; k0 += 32) {
        uint4 aval = {0u, 0u, 0u, 0u};
        if (garow < M) {
            if (AEXT && isf32) {
                const float* Af = (const float*)A;
                u16 t[8];
                #pragma unroll
                for (int j = 0; j < 8; ++j) t[j] = f2bf(Af[(size_t)garow * K + k0 + akk + j]);
                aval = *(uint4*)t;
            } else {
                aval = *(const uint4*)((const u16*)A + (size_t)garow * K + k0 + akk);
            }
        }
        u16 btmp[8];
        #pragma unroll
        for (int j = 0; j < 8; ++j) btmp[j] = ldbf(B, (size_t)(k0 + bkk + j) * N + col0 + bnl, isf32);
        __syncthreads();
        *(uint4*)(&As[arow][akk]) = aval;
        *(uint4*)(&Bs[bnl][bkk]) = *(uint4*)btmp;
        __syncthreads();
        bf16x8 a0 = *(const bf16x8*)(&As[wm + r][quad * 8]);
        bf16x8 a1 = *(const bf16x8*)(&As[wm + 16 + r][quad * 8]);
        bf16x8 b0 = *(const bf16x8*)(&Bs[wn + r][quad * 8]);
        bf16x8 b1 = *(const bf16x8*)(&Bs[wn + 16 + r][quad * 8]);
        acc[0][0] = __builtin_amdgcn_mfma_f32_16x16x32_bf16(a0, b0, acc[0][0], 0, 0, 0);
        acc[0][1] = __builtin_amdgcn_mfma_f32_16x16x32_bf16(a0, b1, acc[0][1], 0, 0, 0);
        acc[1][0] = __builtin_amdgcn_mfma_f32_16x16x32_bf16(a1, b0, acc[1][0], 0, 0, 0);
        acc[1][1] = __builtin_amdgcn_mfma_f32_16x16x32_bf16(a1, b1, acc[1][1], 0, 0, 0);
    }
    #pragma unroll
    for (int i = 0; i < 2; ++i)
        #pragma unroll
        for (int jn = 0; jn < 2; ++jn)
            #pragma unroll
            for (int t = 0; t < 4; ++t) {
                int grow = row0 + wm + i * 16 + quad * 4 + t;
                int gcol = col0 + wn + jn * 16 + r;
                if (grow >= M) continue;
                float v = acc[i][jn][t];
                size_t off = (size_t)grow * N + gcol;
                if (EPI == 0) {
                    ((u16*)Cout)[off] = f2bf(v);
                } else if (EPI == 2) {
                    Rf[off] += v + ldf(bias, gcol, isf32);
                } else {
                    ((float*)Cout)[off] = v + ldf(bias, gcol, isf32) + Rf[off];
                }
            }
}

// ============ FALLBACK: round-4 geglu ============
__global__ __launch_bounds__(256) void k_gemm_geglu(const u16* __restrict__ A, const void* __restrict__ B,
                                                    const void* __restrict__ bias, u16* __restrict__ Out,
                                                    int M, int Nout, int K, int ldb,
                                                    const int* __restrict__ flagp) {
    int isf32 = *flagp;
    __shared__ u16 As[64][40];
    __shared__ u16 Bs[64][40];
    int tid = threadIdx.x;
    int row0 = blockIdx.x * 64, col0 = blockIdx.y * 64;
    int wave = tid >> 6, lane = tid & 63;
    int wm = (wave >> 1) * 32, wn = (wave & 1) * 32;
    int quad = lane >> 4, r = lane & 15;
    int arow = tid >> 2, akk = (tid & 3) * 8;
    int bnl = tid & 63, bkk = (tid >> 6) * 8;
    int garow = row0 + arow;
    f32x4 acc[2][2][2] = {};
    for (int p = 0; p < 2; ++p) {
        for (int k0 = 0; k0 < K; k0 += 32) {
            uint4 aval = {0u, 0u, 0u, 0u};
            if (garow < M) aval = *(const uint4*)(A + (size_t)garow * K + k0 + akk);
            u16 btmp[8];
            #pragma unroll
            for (int j = 0; j < 8; ++j)
                btmp[j] = ldbf(B, (size_t)(k0 + bkk + j) * ldb + p * Nout + col0 + bnl, isf32);
            __syncthreads();
            *(uint4*)(&As[arow][akk]) = aval;
            *(uint4*)(&Bs[bnl][bkk]) = *(uint4*)btmp;
            __syncthreads();
            bf16x8 a0 = *(const bf16x8*)(&As[wm + r][quad * 8]);
            bf16x8 a1 = *(const bf16x8*)(&As[wm + 16 + r][quad * 8]);
            bf16x8 b0 = *(const bf16x8*)(&Bs[wn + r][quad * 8]);
            bf16x8 b1 = *(const bf16x8*)(&Bs[wn + 16 + r][quad * 8]);
            acc[p][0][0] = __builtin_amdgcn_mfma_f32_16x16x32_bf16(a0, b0, acc[p][0][0], 0, 0, 0);
            acc[p][0][1] = __builtin_amdgcn_mfma_f32_16x16x32_bf16(a0, b1, acc[p][0][1], 0, 0, 0);
            acc[p][1][0] = __builtin_amdgcn_mfma_f32_16x16x32_bf16(a1, b0, acc[p][1][0], 0, 0, 0);
            acc[p][1][1] = __builtin_amdgcn_mfma_f32_16x16x32_bf16(a1, b1, acc[p][1][1], 0, 0, 0);
        }
    }
    #pragma unroll
    for (int i = 0; i < 2; ++i)
        #pragma unroll
        for (int jn = 0; jn < 2; ++jn)
            #pragma unroll
            for (int t = 0; t < 4; ++t) {
                int grow = row0 + wm + i * 16 + quad * 4 + t;
                int gcol = col0 + wn + jn * 16 + r;
                if (grow >= M) continue;
                float a = acc[0][i][jn][t] + ldf(bias, gcol, isf32);
                float u = acc[1][i][jn][t] + ldf(bias, Nout + gcol, isf32);
                float th = tanhf(0.7978845608f * (u + 0.044715f * u * u * u));
                float gl = 0.5f * u * (1.f + th);
                Out[(size_t)grow * Nout + gcol] = f2bf(a * gl);
            }
}

// ---------------- MFMA flash attention (parameterized strides) ----------------
__global__ __launch_bounds__(256) void k_attn_flash(const u16* __restrict__ Q, const u16* __restrict__ K,
                                                    const u16* __restrict__ V, u16* __restrict__ O,
                                                    int N, int Mkv, int H, int ldq, int ldkv, int ldo) {
    __shared__ u16 Sp[4][16][40];
    __shared__ u16 VT[64][40];
    int nt = N / 64;
    int qt = blockIdx.x % nt;
    int bh = blockIdx.x / nt;
    int h = bh % H, b = bh / H;
    int tid = threadIdx.x, wave = tid >> 6, lane = tid & 63;
    int quad = lane >> 4, r = lane & 15;
    int q0 = qt * 64 + wave * 16;

    const u16* qbase = Q + ((size_t)(b * N + q0 + r)) * ldq + h * 64;
    bf16x8 aq0 = *(const bf16x8*)(qbase + quad * 8);
    bf16x8 aq1 = *(const bf16x8*)(qbase + 32 + quad * 8);

    f32x4 accO[4] = {};
    float m_i[4] = {-1e30f, -1e30f, -1e30f, -1e30f};
    float l_i[4] = {0.f, 0.f, 0.f, 0.f};

    int vkv = tid & 31, vdg = tid >> 5;

    for (int kv0 = 0; kv0 < Mkv; kv0 += 32) {
        int kr0 = min(kv0 + r, Mkv - 1);
        int kr1 = min(kv0 + 16 + r, Mkv - 1);
        const u16* kb0 = K + ((size_t)(b * Mkv + kr0)) * ldkv + h * 64;
        const u16* kb1 = K + ((size_t)(b * Mkv + kr1)) * ldkv + h * 64;
        bf16x8 bk00 = *(const bf16x8*)(kb0 + quad * 8);
        bf16x8 bk01 = *(const bf16x8*)(kb0 + 32 + quad * 8);
        bf16x8 bk10 = *(const bf16x8*)(kb1 + quad * 8);
        bf16x8 bk11 = *(const bf16x8*)(kb1 + 32 + quad * 8);
        int vrow = min(kv0 + vkv, Mkv - 1);
        uint4 vv = *(const uint4*)(V + ((size_t)(b * Mkv + vrow)) * ldkv + h * 64 + vdg * 8);

        __syncthreads();
        VT[vdg * 8 + 0][vkv] = (u16)(vv.x);
        VT[vdg * 8 + 1][vkv] = (u16)(vv.x >> 16);
        VT[vdg * 8 + 2][vkv] = (u16)(vv.y);
        VT[vdg * 8 + 3][vkv] = (u16)(vv.y >> 16);
        VT[vdg * 8 + 4][vkv] = (u16)(vv.z);
        VT[vdg * 8 + 5][vkv] = (u16)(vv.z >> 16);
        VT[vdg * 8 + 6][vkv] = (u16)(vv.w);
        VT[vdg * 8 + 7][vkv] = (u16)(vv.w >> 16);
        __syncthreads();

        f32x4 s0 = {}, s1 = {};
        s0 = __builtin_amdgcn_mfma_f32_16x16x32_bf16(aq0, bk00, s0, 0, 0, 0);
        s0 = __builtin_amdgcn_mfma_f32_16x16x32_bf16(aq1, bk01, s0, 0, 0, 0);
        s1 = __builtin_amdgcn_mfma_f32_16x16x32_bf16(aq0, bk10, s1, 0, 0, 0);
        s1 = __builtin_amdgcn_mfma_f32_16x16x32_bf16(aq1, bk11, s1, 0, 0, 0);
        bool mask0 = (kv0 + r) >= Mkv;
        bool mask1 = (kv0 + 16 + r) >= Mkv;

        #pragma unroll
        for (int t = 0; t < 4; ++t) {
            float a = mask0 ? -1e30f : s0[t] * 0.125f;
            float c = mask1 ? -1e30f : s1[t] * 0.125f;
            float mx = fmaxf(a, c);
            mx = fmaxf(mx, __shfl_xor(mx, 1));
            mx = fmaxf(mx, __shfl_xor(mx, 2));
            mx = fmaxf(mx, __shfl_xor(mx, 4));
            mx = fmaxf(mx, __shfl_xor(mx, 8));
            float mn = fmaxf(m_i[t], mx);
            float alpha = __expf(m_i[t] - mn);
            float p0 = __expf(a - mn);
            float p1 = __expf(c - mn);
            float ps = p0 + p1;
            ps += __shfl_xor(ps, 1);
            ps += __shfl_xor(ps, 2);
            ps += __shfl_xor(ps, 4);
            ps += __shfl_xor(ps, 8);
            l_i[t] = l_i[t] * alpha + ps;
            m_i[t] = mn;
            accO[0][t] *= alpha; accO[1][t] *= alpha; accO[2][t] *= alpha; accO[3][t] *= alpha;
            Sp[wave][quad * 4 + t][r] = f2bf(p0);
            Sp[wave][quad * 4 + t][16 + r] = f2bf(p1);
        }

        bf16x8 ap = *(const bf16x8*)(&Sp[wave][r][quad * 8]);
        #pragma unroll
        for (int g = 0; g < 4; ++g) {
            bf16x8 bvv = *(const bf16x8*)(&VT[g * 16 + r][quad * 8]);
            accO[g] = __builtin_amdgcn_mfma_f32_16x16x32_bf16(ap, bvv, accO[g], 0, 0, 0);
        }
    }

    u16* ob = O + ((size_t)(b * N + q0)) * ldo + h * 64;
    #pragma unroll
    for (int t = 0; t < 4; ++t) {
        float inv = 1.f / l_i[t];
        #pragma unroll
        for (int g = 0; g < 4; ++g)
            ob[(size_t)(quad * 4 + t) * ldo + g * 16 + r] = f2bf(accO[g][t] * inv);
    }
}

extern "C" void kernel_launch(void* const* d_in, const int* in_sizes, int n_in,
                              void* d_out, int out_size, void* d_ws, size_t ws_size,
                              hipStream_t stream) {
    const void* x    = d_in[0];
    const void* ctx  = d_in[1];
    const void* g1   = d_in[2];
    const void* be1  = d_in[3];
    const void* wq1  = d_in[4];
    const void* wk1  = d_in[5];
    const void* wv1  = d_in[6];
    const void* wo1  = d_in[7];
    const void* bo1  = d_in[8];
    const void* g2   = d_in[9];
    const void* be2  = d_in[10];
    const void* wq2  = d_in[11];
    const void* wk2  = d_in[12];
    const void* wv2  = d_in[13];
    const void* wo2  = d_in[14];
    const void* bo2  = d_in[15];
    const void* g3   = d_in[16];
    const void* be3  = d_in[17];
    const void* wff1 = d_in[18];
    const void* bff1 = d_in[19];
    const void* wff2 = d_in[20];
    const void* bff2 = d_in[21];

    const int BT = 4096, D = 1280;
    dim3 blk(256);
    char* ws = (char*)d_ws;

    const size_t NEED_FAST = 117393664;
    if (ws_size >= NEED_FAST) {
        // ---------- fast path ----------
        int*   flag   = (int*)(ws);
        u16* lnout    = (u16*)(ws + 256);            // 4096x1280 bf16
        u16* qkv      = (u16*)(ws + 10486016);       // 4096x3840 bf16 (region R)
        u16* attnout  = (u16*)(ws + 10486016 + 31457280);
        u16* gbuf     = (u16*)(ws + 10486016);       // 4096x5120 bf16, aliases qkv+attnout
        u16* ctxb     = (u16*)(ws + 52429056);       // 308x768 bf16
        u16* kv2      = (u16*)(ws + 52902144);       // 308x2560 bf16
        u16* wqkv1t   = (u16*)(ws + 54479104);       // [3840][1280]
        u16* wo1t     = (u16*)(ws + 64309504);       // [1280][1280]
        u16* wq2t     = (u16*)(ws + 67586304);
        u16* wkv2t    = (u16*)(ws + 70863104);       // [2560][768]
        u16* wo2t     = (u16*)(ws + 74795264);
        u16* wff1t    = (u16*)(ws + 78072064);       // [10240][1280]
        u16* wff2t    = (u16*)(ws + 104286464);      // [1280][5120]
        float* pff2   = (float*)(ws + 54479104);     // FF2 split-K partial (21 MB), reuses dead
                                                     // wqkv1t/wo1t region (last read: QKV/WO1 GEMMs,
                                                     // both before FF2; re-transposed next launch)
        float* xres   = (float*)d_out;               // residual lives in the fp32 output

        k_detect<<<dim3(1), blk, 0, stream>>>((const u16*)x, flag);
        k_b2f<<<dim3((BT * D + 255) / 256), blk, 0, stream>>>(x, xres, BT * D, flag);
        // weight transposes (once per launch)
        k_transpose<<<dim3(40, 40), blk, 0, stream>>>(wq1, wqkv1t, 1280, 1280, flag);
        k_transpose<<<dim3(40, 40), blk, 0, stream>>>(wk1, wqkv1t + 1280 * 1280, 1280, 1280, flag);
        k_transpose<<<dim3(40, 40), blk, 0, stream>>>(wv1, wqkv1t + 2 * 1280 * 1280, 1280, 1280, flag);
        k_transpose<<<dim3(40, 40), blk, 0, stream>>>(wo1, wo1t, 1280, 1280, flag);
        k_transpose<<<dim3(40, 40), blk, 0, stream>>>(wq2, wq2t, 1280, 1280, flag);
        k_transpose<<<dim3(24, 40), blk, 0, stream>>>(wk2, wkv2t, 768, 1280, flag);
        k_transpose<<<dim3(24, 40), blk, 0, stream>>>(wv2, wkv2t + 1280 * 768, 768, 1280, flag);
        k_transpose<<<dim3(40, 40), blk, 0, stream>>>(wo2, wo2t, 1280, 1280, flag);
        k_transpose<<<dim3(40, 320), blk, 0, stream>>>(wff1, wff1t, 1280, 10240, flag);
        k_transpose<<<dim3(160, 40), blk, 0, stream>>>(wff2, wff2t, 5120, 1280, flag);
        k_cvt<<<dim3((308 * 768 + 255) / 256), blk, 0, stream>>>(ctx, ctxb, 308 * 768, flag);
        // --- self attention ---
        k_layernorm<<<dim3(BT), blk, 0, stream>>>(xres, g1, be1, lnout, D, flag);
        k_gemm8<0><<<dim3(16, 15), dim3(512), 0, stream>>>(lnout, wqkv1t, qkv, nullptr, BT, 3840, D, flag);
        k_attn_flash<<<dim3(16 * 80), blk, 0, stream>>>(qkv, qkv + 1280, qkv + 2560, attnout,
                                                        1024, 1024, 20, 3840, 3840, 1280);
        k_gemm_t<2><<<dim3(32, 10), blk, 0, stream>>>(attnout, wo1t, nullptr, xres, bo1, BT, D, D, flag);
        // --- cross attention ---
        k_layernorm<<<dim3(BT), blk, 0, stream>>>(xres, g2, be2, lnout, D, flag);
        k_gemm_t<0><<<dim3(32, 10), blk, 0, stream>>>(lnout, wq2t, qkv, nullptr, nullptr, BT, D, D, flag);
        k_gemm_t<0><<<dim3(3, 20), blk, 0, stream>>>(ctxb, wkv2t, kv2, nullptr, nullptr, 308, 2560, 768, flag);
        k_attn_flash<<<dim3(16 * 80), blk, 0, stream>>>(qkv, kv2, kv2 + 1280, attnout,
                                                        1024, 77, 20, 1280, 2560, 1280);
        k_gemm_t<2><<<dim3(32, 10), blk, 0, stream>>>(attnout, wo2t, nullptr, xres, bo2, BT, D, D, flag);
        // --- GEGLU FF ---
        k_layernorm<<<dim3(BT), blk, 0, stream>>>(xres, g3, be3, lnout, D, flag);
        k_gemm8<1><<<dim3(16, 40), dim3(512), 0, stream>>>(lnout, wff1t, gbuf, bff1, BT, 10240, D, flag);
        // FF2: split-K=2, no atomics: kz0 -> xres (+bias), kz1 -> pff2; then fold.
        k_gemm_t<2><<<dim3(32, 10, 2), blk, 0, stream>>>(gbuf, wff2t, pff2, xres, bff2, BT, D, 5120, flag);
        k_addp<<<dim3(2048), blk, 0, stream>>>(xres, pff2, BT * D / 4);
    } else {
        // ---------- fallback: round-4 path (known-good, ~75 MB ws) ----------
        int*   flag    = (int*)(ws);
        float* xres    = (float*)(ws + 256);
        u16* lnout     = (u16*)(ws + 20971776);
        u16* q         = (u16*)(ws + 31457536);
        u16* kbuf      = (u16*)(ws + 41943296);
        u16* vbuf      = (u16*)(ws + 52429056);
        u16* attnout   = (u16*)(ws + 62914816);
        u16* k2        = (u16*)(ws + 73400576);
        u16* v2        = (u16*)(ws + 74189056);
        u16* gbuf      = (u16*)(ws + 31457536);

        dim3 g_gemm(64, 20);
        dim3 g_kv(5, 20);
        dim3 g_attn(16 * 80);

        k_detect<<<dim3(1), blk, 0, stream>>>((const u16*)x, flag);
        k_b2f<<<dim3((BT * D + 255) / 256), blk, 0, stream>>>(x, xres, BT * D, flag);
        k_layernorm<<<dim3(BT), blk, 0, stream>>>(xres, g1, be1, lnout, D, flag);
        k_gemm<0, false><<<g_gemm, blk, 0, stream>>>(lnout, wq1, q, nullptr, nullptr, BT, D, D, flag);
        k_gemm<0, false><<<g_gemm, blk, 0, stream>>>(lnout, wk1, kbuf, nullptr, nullptr, BT, D, D, flag);
        k_gemm<0, false><<<g_gemm, blk, 0, stream>>>(lnout, wv1, vbuf, nullptr, nullptr, BT, D, D, flag);
        k_attn_flash<<<g_attn, blk, 0, stream>>>(q, kbuf, vbuf, attnout, 1024, 1024, 20, 1280, 1280, 1280);
        k_gemm<2, false><<<g_gemm, blk, 0, stream>>>(attnout, wo1, nullptr, xres, bo1, BT, D, D, flag);
        k_layernorm<<<dim3(BT), blk, 0, stream>>>(xres, g2, be2, lnout, D, flag);
        k_gemm<0, false><<<g_gemm, blk, 0, stream>>>(lnout, wq2, q, nullptr, nullptr, BT, D, D, flag);
        k_gemm<0, true><<<g_kv, blk, 0, stream>>>(ctx, wk2, k2, nullptr, nullptr, 308, D, 768, flag);
        k_gemm<0, true><<<g_kv, blk, 0, stream>>>(ctx, wv2, v2, nullptr, nullptr, 308, D, 768, flag);
        k_attn_flash<<<g_attn, blk, 0, stream>>>(q, k2, v2, attnout, 1024, 77, 20, 1280, 1280, 1280);
        k_gemm<2, false><<<g_gemm, blk, 0, stream>>>(attnout, wo2, nullptr, xres, bo2, BT, D, D, flag);
        k_layernorm<<<dim3(BT), blk, 0, stream>>>(xres, g3, be3, lnout, D, flag);
        k_gemm_geglu<<<dim3(64, 80), blk, 0, stream>>>(lnout, wff1, bff1, gbuf, BT, 5120, D, 10240, flag);
        k_gemm<3, false><<<g_gemm, blk, 0, stream>>>(gbuf, wff2, d_out, xres, bff2, BT, D, 5120, flag);
    }
}

// Round 8
// 831.361 us; speedup vs baseline: 1.0122x; 1.0122x over previous
//
#include <hip/hip_runtime.h>

typedef unsigned short u16;
typedef __bf16 bf16x8 __attribute__((ext_vector_type(8)));
typedef float f32x4 __attribute__((ext_vector_type(4)));

static __device__ __forceinline__ float bf2f(u16 u) {
    union { unsigned int i; float f; } v; v.i = ((unsigned int)u) << 16; return v.f;
}
static __device__ __forceinline__ u16 f2bf(float f) {
    union { float f; unsigned int i; } v; v.f = f;
    unsigned int b = v.i;
    b += 0x7fffu + ((b >> 16) & 1u);   // RNE
    return (u16)(b >> 16);
}
static __device__ __forceinline__ u16 ldbf(const void* p, size_t i, int isf32) {
    return isf32 ? f2bf(((const float*)p)[i]) : ((const u16*)p)[i];
}
static __device__ __forceinline__ float ldf(const void* p, size_t i, int isf32) {
    return isf32 ? ((const float*)p)[i] : bf2f(((const u16*)p)[i]);
}
// async global->LDS, 16B per lane; lds dest = wave-uniform base + lane*16 (m97/m104)
static __device__ __forceinline__ void glds16(const u16* g, u16* l) {
    __builtin_amdgcn_global_load_lds(
        (const __attribute__((address_space(1))) unsigned int*)g,
        (__attribute__((address_space(3))) unsigned int*)l,
        16, 0, 0);
}
// XCD-chunked bijective remap (T1, m192). Used ONLY for k_gemm8.
static __device__ __forceinline__ int xcd_swz(int lid, int nwg) {
    return ((nwg & 7) == 0) ? ((lid & 7) * (nwg >> 3) + (lid >> 3)) : lid;
}

// ---------------- dtype detector (insurance; inputs measured fp32) ----------------
__global__ __launch_bounds__(256) void k_detect(const u16* __restrict__ xu, int* __restrict__ flag) {
    u16 v = xu[threadIdx.x * 2];
    int e = (v >> 7) & 0xFF;
    int sane = (e >= 87 && e <= 133) ? 1 : 0;
    int total = __syncthreads_count(sane);
    if (threadIdx.x == 0) flag[0] = (total < 192) ? 1 : 0;
}

// ---------------- x -> f32 residual stream ----------------
__global__ __launch_bounds__(256) void k_b2f(const void* __restrict__ in, float* __restrict__ out, int n,
                                             const int* __restrict__ flagp) {
    int isf32 = *flagp;
    int i = blockIdx.x * 256 + threadIdx.x;
    if (i < n) out[i] = ldf(in, i, isf32);
}

// ---------------- external -> bf16 convert ----------------
__global__ __launch_bounds__(256) void k_cvt(const void* __restrict__ in, u16* __restrict__ out, int n,
                                             const int* __restrict__ flagp) {
    int isf32 = *flagp;
    int i = blockIdx.x * 256 + threadIdx.x;
    if (i < n) out[i] = ldbf(in, i, isf32);
}

// ---------------- split-K reduce: X += P (fp32, vectorized) ----------------
__global__ __launch_bounds__(256) void k_addp(float* __restrict__ X, const float* __restrict__ P, int n4) {
    int i = blockIdx.x * 256 + threadIdx.x;
    int stride = gridDim.x * 256;
    for (; i < n4; i += stride) {
        f32x4 a = ((const f32x4*)X)[i];
        f32x4 b = ((const f32x4*)P)[i];
        a[0] += b[0]; a[1] += b[1]; a[2] += b[2]; a[3] += b[3];
        ((f32x4*)X)[i] = a;
    }
}

// ---------------- weight transpose+convert: W[K,N] (ext) -> Wt[N,K] bf16 ----------------
__global__ __launch_bounds__(256) void k_transpose(const void* __restrict__ W, u16* __restrict__ Wt,
                                                   int K, int N, const int* __restrict__ flagp) {
    int isf32 = *flagp;
    __shared__ u16 T[32][33];
    int k0 = blockIdx.x * 32, n0 = blockIdx.y * 32;
    int tid = threadIdx.x;
    int c = tid & 31, rr = tid >> 5;
    #pragma unroll
    for (int j = 0; j < 4; ++j) {
        int k = rr + j * 8;
        T[k][c] = ldbf(W, (size_t)(k0 + k) * N + n0 + c, isf32);
    }
    __syncthreads();
    #pragma unroll
    for (int j = 0; j < 4; ++j) {
        int n = rr + j * 8;
        Wt[(size_t)(n0 + n) * K + k0 + c] = T[c][n];
    }
}

// ---------------- batched transpose: up to 3 same-shape weights in one launch ----------------
__global__ __launch_bounds__(256) void k_transpose3(const void* __restrict__ W0, const void* __restrict__ W1,
                                                    const void* __restrict__ W2,
                                                    u16* __restrict__ D0, u16* __restrict__ D1,
                                                    u16* __restrict__ D2,
                                                    int K, int N, const int* __restrict__ flagp) {
    int isf32 = *flagp;
    int z = blockIdx.z;
    const void* W = (z == 0) ? W0 : (z == 1) ? W1 : W2;
    u16* Wt = (z == 0) ? D0 : (z == 1) ? D1 : D2;
    __shared__ u16 T[32][33];
    int k0 = blockIdx.x * 32, n0 = blockIdx.y * 32;
    int tid = threadIdx.x;
    int c = tid & 31, rr = tid >> 5;
    #pragma unroll
    for (int j = 0; j < 4; ++j) {
        int k = rr + j * 8;
        T[k][c] = ldbf(W, (size_t)(k0 + k) * N + n0 + c, isf32);
    }
    __syncthreads();
    #pragma unroll
    for (int j = 0; j < 4; ++j) {
        int n = rr + j * 8;
        Wt[(size_t)(n0 + n) * K + k0 + c] = T[c][n];
    }
}

// ---------------- LayerNorm: fp32 in -> bf16 out; optional split-K partial fold ----------------
// If P != null: x[i] += P[i] first (residual write-back), then normalize the summed value.
__global__ __launch_bounds__(256) void k_layernorm(float* __restrict__ X, const float* __restrict__ P,
                                                   const void* __restrict__ G, const void* __restrict__ Bb,
                                                   u16* __restrict__ Y, int D,
                                                   const int* __restrict__ flagp) {
    int isf32 = *flagp;
    int row = blockIdx.x;
    float* xr = X + (size_t)row * D;
    const float* pr = P ? (P + (size_t)row * D) : nullptr;
    float s = 0.f, s2 = 0.f;
    for (int i = threadIdx.x; i < D; i += 256) {
        float v = xr[i] + (P ? pr[i] : 0.f);
        s += v; s2 += v * v;
    }
    #pragma unroll
    for (int off = 32; off; off >>= 1) { s += __shfl_down(s, off); s2 += __shfl_down(s2, off); }
    __shared__ float rs[4], rs2[4];
    __shared__ float stat[2];
    int w = threadIdx.x >> 6;
    if ((threadIdx.x & 63) == 0) { rs[w] = s; rs2[w] = s2; }
    __syncthreads();
    if (threadIdx.x == 0) {
        float ts = rs[0] + rs[1] + rs[2] + rs[3];
        float ts2 = rs2[0] + rs2[1] + rs2[2] + rs2[3];
        float mu = ts / D;
        float var = ts2 / D - mu * mu;
        stat[0] = mu; stat[1] = rsqrtf(var + 1e-5f);
    }
    __syncthreads();
    float mu = stat[0], rstd = stat[1];
    u16* yr = Y + (size_t)row * D;
    for (int i = threadIdx.x; i < D; i += 256) {
        float v = xr[i] + (P ? pr[i] : 0.f);
        if (P) xr[i] = v;                      // residual stream now holds the full sum
        yr[i] = f2bf((v - mu) * rstd * ldf(G, i, isf32) + ldf(Bb, i, isf32));
    }
}

// ============ 256x256 GEMM, overlapped 4-phase schedule (T1..T5 + counted-lgkm) ============
// (unchanged from round 7 -- three schedule variants measured identical; parked)
template <int EPI>
__global__ __launch_bounds__(512, 2) void k_gemm8(const u16* __restrict__ A, const u16* __restrict__ Bt,
                                                  void* __restrict__ Cout, const void* __restrict__ bias,
                                                  int M, int N, int K, const int* __restrict__ flagp) {
    __shared__ __align__(16) u16 sm[65536];   // 128 KiB static
    const int tid = threadIdx.x;
    const int w = tid >> 6;
    const int lane = tid & 63;
    const int quad = lane >> 4, r = lane & 15;
    const int wm = w >> 2, wn = w & 3;          // 2 x 4 wave grid
    const int lid = blockIdx.x + blockIdx.y * gridDim.x;
    const int nid = xcd_swz(lid, gridDim.x * gridDim.y);
    const int row0 = (nid % gridDim.x) * 256;
    const int col0 = (nid / gridDim.x) * 256;
    const int NT = K >> 6;

    const u16* aP[2][2];
    const u16* bP[2][2];
    #pragma unroll
    for (int j = 0; j < 2; ++j) {
        int c = tid + w * 64 + j * 64;          // = w*128 + j*64 + lane
        int rj = c >> 3;                        // row within half (0..127)
        int qe = (c & 7) ^ (rj & 7);            // inverse-swizzled global chunk
        #pragma unroll
        for (int h = 0; h < 2; ++h) {
            int gr = h * 128 + rj;
            aP[h][j] = A + (size_t)(row0 + gr) * K + qe * 8;
            int n = col0 + gr;
            int m = (EPI == 1) ? (((n >> 4) & 1) * 5120 + (n >> 5) * 16 + (n & 15)) : n;
            bP[h][j] = Bt + (size_t)m * K + qe * 8;
        }
    }
    auto stageA = [&](int h, int t) {
        u16* base = sm + (t & 1) * 32768 + h * 8192 + w * 1024;
        glds16(aP[h][0] + t * 64, base);
        glds16(aP[h][1] + t * 64, base + 512);
    };
    auto stageB = [&](int h, int t) {
        u16* base = sm + (t & 1) * 32768 + 16384 + h * 8192 + w * 1024;
        glds16(bP[h][0] + t * 64, base);
        glds16(bP[h][1] + t * 64, base + 512);
    };

    f32x4 acc[2][2][4][2] = {};
    const int xq = r & 7;
    bf16x8 afA[4][2], afB[4][2], bf0[2][2], bf1[2][2];

    auto readA = [&](bf16x8 (&dst)[4][2], int Ab, int half) {
        #pragma unroll
        for (int i = 0; i < 4; ++i) {
            int ar = half * 128 + wm * 64 + i * 16 + r;
            #pragma unroll
            for (int ks = 0; ks < 2; ++ks)
                dst[i][ks] = *(const bf16x8*)(sm + Ab + ar * 64 + (((ks * 4 + quad) ^ xq) * 8));
        }
    };
    auto readB = [&](bf16x8 (&dst)[2][2], int Bb, int half) {
        #pragma unroll
        for (int g = 0; g < 2; ++g) {
            int br = half * 128 + wn * 32 + g * 16 + r;
            #pragma unroll
            for (int ks = 0; ks < 2; ++ks)
                dst[g][ks] = *(const bf16x8*)(sm + Bb + br * 64 + (((ks * 4 + quad) ^ xq) * 8));
        }
    };
    auto domfma = [&](int qm, int qn, bf16x8 (&a)[4][2], bf16x8 (&b)[2][2]) {
        #pragma unroll
        for (int ks = 0; ks < 2; ++ks)
            #pragma unroll
            for (int i = 0; i < 4; ++i)
                #pragma unroll
                for (int g = 0; g < 2; ++g)
                    acc[qm][qn][i][g] = __builtin_amdgcn_mfma_f32_16x16x32_bf16(
                        a[i][ks], b[g][ks], acc[qm][qn][i][g], 0, 0, 0);
    };

    // prologue: tile 0 complete + halves0 of tile 1; vmcnt(4) -> tile 0 landed
    stageA(0, 0); stageB(0, 0); stageA(1, 0); stageB(1, 0);
    if (NT > 1) {
        stageA(0, 1); stageB(0, 1);
        asm volatile("s_waitcnt vmcnt(4)" ::: "memory");
    } else {
        asm volatile("s_waitcnt vmcnt(0)" ::: "memory");
    }
    __builtin_amdgcn_s_barrier();
    readA(afA, 0, 0);
    readB(bf0, 16384, 0);

    for (int t = 0; t < NT; ++t) {
        const int Ab = (t & 1) * 32768;
        const int Bb = Ab + 16384;
        const int Abn = ((t + 1) & 1) * 32768;
        // ---- ph0: MFMA(afA,bf0); prefetch bf1 under it ----
        readB(bf1, Bb, 1);
        __builtin_amdgcn_sched_barrier(0);
        __builtin_amdgcn_s_setprio(1);
        domfma(0, 0, afA, bf0);
        __builtin_amdgcn_s_setprio(0);
        if (t + 1 < NT) stageA(1, t + 1);
        __builtin_amdgcn_s_barrier();
        // ---- ph1: MFMA(afA,bf1); prefetch afB under it ----
        readA(afB, Ab, 1);
        __builtin_amdgcn_sched_barrier(0);
        __builtin_amdgcn_s_setprio(1);
        domfma(0, 1, afA, bf1);
        __builtin_amdgcn_s_setprio(0);
        if (t + 1 < NT) stageB(1, t + 1);
        __builtin_amdgcn_s_barrier();
        // ---- ph2: MFMA(afB,bf1) ----
        __builtin_amdgcn_s_setprio(1);
        domfma(1, 1, afB, bf1);
        __builtin_amdgcn_s_setprio(0);
        if (t + 2 < NT) stageA(0, t + 2);
        __builtin_amdgcn_s_barrier();
        // ---- ph3: MFMA(afB,bf0); vmcnt-gate + next-tile frag issue ----
        __builtin_amdgcn_s_setprio(1);
        domfma(1, 0, afB, bf0);
        __builtin_amdgcn_s_setprio(0);
        if (t + 2 < NT) stageB(0, t + 2);
        if (t + 2 < NT) asm volatile("s_waitcnt vmcnt(4)" ::: "memory");
        else            asm volatile("s_waitcnt vmcnt(0)" ::: "memory");
        __builtin_amdgcn_s_barrier();
        if (t + 1 < NT) {
            readA(afA, Abn, 0);
            readB(bf0, Abn + 16384, 0);
        }
    }

    if (EPI == 0) {
        u16* C = (u16*)Cout;
        #pragma unroll
        for (int qm = 0; qm < 2; ++qm) {
            #pragma unroll
            for (int qn = 0; qn < 2; ++qn) {
                #pragma unroll
                for (int i = 0; i < 4; ++i) {
                    int grow = row0 + qm * 128 + wm * 64 + i * 16 + quad * 4;
                    #pragma unroll
                    for (int g = 0; g < 2; ++g) {
                        int gcol = col0 + qn * 128 + wn * 32 + g * 16 + r;
                        #pragma unroll
                        for (int t4 = 0; t4 < 4; ++t4)
                            C[(size_t)(grow + t4) * N + gcol] = f2bf(acc[qm][qn][i][g][t4]);
                    }
                }
            }
        }
    } else {
        const int isf32 = *flagp;
        u16* C = (u16*)Cout;  // [M][5120]
        #pragma unroll
        for (int qm = 0; qm < 2; ++qm) {
            #pragma unroll
            for (int qn = 0; qn < 2; ++qn) {
                int ncb = col0 + qn * 128 + wn * 32;
                int oc = (ncb >> 1) + r;
                float bva = ldf(bias, oc, isf32);
                float bvu = ldf(bias, 5120 + oc, isf32);
                #pragma unroll
                for (int i = 0; i < 4; ++i) {
                    int grow = row0 + qm * 128 + wm * 64 + i * 16 + quad * 4;
                    #pragma unroll
                    for (int t4 = 0; t4 < 4; ++t4) {
                        float a = acc[qm][qn][i][0][t4] + bva;
                        float u = acc[qm][qn][i][1][t4] + bvu;
                        float z2 = 1.5957691216f * (u + 0.044715f * u * u * u);
                        float gl = u * __builtin_amdgcn_rcpf(1.f + __expf(-z2));
                        C[(size_t)(grow + t4) * 5120 + oc] = f2bf(a * gl);
                    }
                }
            }
        }
    }
}

// ============ FAST PATH: 128x128 tile GEMM via global_load_lds, xor-swizzled LDS ============
// EPI: 0 = bf16 store; 2 = xres += acc + bias (fp32). Split-K (gridDim.z==2):
// kz=0 -> xres += acc + bias (non-atomic, sole owner); kz=1 -> fp32 partial into Cout;
// the partial is folded by k_addp or by the following k_layernorm(P=partial).
template <int EPI>
__global__ __launch_bounds__(256) void k_gemm_t(const u16* __restrict__ A, const u16* __restrict__ Bt,
                                                void* __restrict__ Cout, float* __restrict__ Rf,
                                                const void* __restrict__ bias,
                                                int M, int N, int K, const int* __restrict__ flagp) {
    int isf32 = *flagp;
    __shared__ __align__(16) u16 As[4096];
    __shared__ __align__(16) u16 Bs[4096];
    int tid = threadIdx.x;
    int row0 = blockIdx.x * 128, col0 = blockIdx.y * 128;
    int S = gridDim.z, kz = blockIdx.z;
    int kseg = K / S;
    int kb = kz * kseg, ke = kb + kseg;
    int wave = tid >> 6, lane = tid & 63;
    int wm = (wave >> 1) * 64, wn = (wave & 1) * 64;
    int quad = lane >> 4, r = lane & 15;
    int c0 = wave * 64 + lane, c1 = 256 + c0;
    int ar0 = c0 >> 2, aq0 = (c0 & 3) ^ ((ar0 >> 1) & 3);
    int ar1 = c1 >> 2, aq1 = (c1 & 3) ^ ((ar1 >> 1) & 3);
    const u16* Ag0 = A + (size_t)min(row0 + ar0, M - 1) * K + aq0 * 8;
    const u16* Ag1 = A + (size_t)min(row0 + ar1, M - 1) * K + aq1 * 8;
    const u16* Bg0 = Bt + (size_t)(col0 + ar0) * K + aq0 * 8;
    const u16* Bg1 = Bt + (size_t)(col0 + ar1) * K + aq1 * 8;
    u16* lA0 = As + wave * 512;
    u16* lA1 = As + 2048 + wave * 512;
    u16* lB0 = Bs + wave * 512;
    u16* lB1 = Bs + 2048 + wave * 512;
    f32x4 acc[4][4] = {};
    for (int k0 = kb; k0 < ke; k0 += 32) {
        __syncthreads();
        glds16(Ag0 + k0, lA0);
        glds16(Ag1 + k0, lA1);
        glds16(Bg0 + k0, lB0);
        glds16(Bg1 + k0, lB1);
        __syncthreads();
        bf16x8 af[4], bfv[4];
        #pragma unroll
        for (int i = 0; i < 4; ++i) {
            int row = wm + i * 16 + r;
            af[i] = *(const bf16x8*)(As + (row * 4 + (quad ^ ((row >> 1) & 3))) * 8);
        }
        #pragma unroll
        for (int g = 0; g < 4; ++g) {
            int row = wn + g * 16 + r;
            bfv[g] = *(const bf16x8*)(Bs + (row * 4 + (quad ^ ((row >> 1) & 3))) * 8);
        }
        #pragma unroll
        for (int i = 0; i < 4; ++i)
            #pragma unroll
            for (int g = 0; g < 4; ++g)
                acc[i][g] = __builtin_amdgcn_mfma_f32_16x16x32_bf16(af[i], bfv[g], acc[i][g], 0, 0, 0);
    }
    #pragma unroll
    for (int i = 0; i < 4; ++i) {
        int grow = row0 + wm + i * 16 + quad * 4;
        if (grow >= M) continue;
        #pragma unroll
        for (int g = 0; g < 4; ++g) {
            int gcol = col0 + wn + g * 16 + r;
            float bv = (EPI == 2 && kz == 0) ? ldf(bias, gcol, isf32) : 0.f;
            #pragma unroll
            for (int t = 0; t < 4; ++t) {
                float v = acc[i][g][t];
                size_t off = (size_t)(grow + t) * N + gcol;
                if (EPI == 0) {
                    ((u16*)Cout)[off] = f2bf(v);
                } else {
                    if (kz == 0) Rf[off] += v + bv;          // sole owner of this element in z=0
                    else         ((float*)Cout)[off] = v;    // partial; folded later
                }
            }
        }
    }
}

// ============ FAST PATH: GEGLU ff1 via global_load_lds; Nout=5120 (fallback for gemm8) ====
__global__ __launch_bounds__(256) void k_geglu_t(const u16* __restrict__ A, const u16* __restrict__ Bt,
                                                 const void* __restrict__ bias, u16* __restrict__ Out,
                                                 int M, int K, const int* __restrict__ flagp) {
    const int Nout = 5120;
    int isf32 = *flagp;
    __shared__ __align__(16) u16 As[4096];
    __shared__ __align__(16) u16 Bs[4096];
    int tid = threadIdx.x;
    int row0 = blockIdx.x * 128, col0 = blockIdx.y * 64;
    int wave = tid >> 6, lane = tid & 63;
    int quad = lane >> 4, r = lane & 15;
    int c0 = wave * 64 + lane, c1 = 256 + c0;
    int ar0 = c0 >> 2, aq0 = (c0 & 3) ^ ((ar0 >> 1) & 3);
    int ar1 = c1 >> 2, aq1 = (c1 & 3) ^ ((ar1 >> 1) & 3);
    const u16* Ag0 = A + (size_t)min(row0 + ar0, M - 1) * K + aq0 * 8;
    const u16* Ag1 = A + (size_t)min(row0 + ar1, M - 1) * K + aq1 * 8;
    const u16* Bg0 = Bt + (size_t)((ar0 >> 6) * Nout + col0 + (ar0 & 63)) * K + aq0 * 8;
    const u16* Bg1 = Bt + (size_t)((ar1 >> 6) * Nout + col0 + (ar1 & 63)) * K + aq1 * 8;
    u16* lA0 = As + wave * 512;
    u16* lA1 = As + 2048 + wave * 512;
    u16* lB0 = Bs + wave * 512;
    u16* lB1 = Bs + 2048 + wave * 512;
    f32x4 acc[2][2][4] = {};
    for (int k0 = 0; k0 < K; k0 += 32) {
        __syncthreads();
        glds16(Ag0 + k0, lA0);
        glds16(Ag1 + k0, lA1);
        glds16(Bg0 + k0, lB0);
        glds16(Bg1 + k0, lB1);
        __syncthreads();
        bf16x8 af[2], bv[2][4];
        #pragma unroll
        for (int i = 0; i < 2; ++i) {
            int row = wave * 32 + i * 16 + r;
            af[i] = *(const bf16x8*)(As + (row * 4 + (quad ^ ((row >> 1) & 3))) * 8);
        }
        #pragma unroll
        for (int p = 0; p < 2; ++p)
            #pragma unroll
            for (int g = 0; g < 4; ++g) {
                int row = p * 64 + g * 16 + r;
                bv[p][g] = *(const bf16x8*)(Bs + (row * 4 + (quad ^ ((row >> 1) & 3))) * 8);
            }
        #pragma unroll
        for (int p = 0; p < 2; ++p)
            #pragma unroll
            for (int i = 0; i < 2; ++i)
                #pragma unroll
                for (int g = 0; g < 4; ++g)
                    acc[p][i][g] = __builtin_amdgcn_mfma_f32_16x16x32_bf16(af[i], bv[p][g], acc[p][i][g], 0, 0, 0);
    }
    #pragma unroll
    for (int i = 0; i < 2; ++i) {
        int grow = row0 + wave * 32 + i * 16 + quad * 4;
        #pragma unroll
        for (int g = 0; g < 4; ++g) {
            int gcol = col0 + g * 16 + r;
            float bva = ldf(bias, gcol, isf32);
            float bvu = ldf(bias, Nout + gcol, isf32);
            #pragma unroll
            for (int t = 0; t < 4; ++t) {
                float a = acc[0][i][g][t] + bva;
                float u = acc[1][i][g][t] + bvu;
                float z2 = 1.5957691216f * (u + 0.044715f * u * u * u);
                float gl = u * __builtin_amdgcn_rcpf(1.f + __expf(-z2));
                Out[(size_t)(grow + t) * Nout + gcol] = f2bf(a * gl);
            }
        }
    }
}

// ============ FALLBACK: round-4 64x64 GEMM (known-good) ============
template <int EPI, bool AEXT>
__global__ __launch_bounds__(256) void k_gemm(const void* __restrict__ A, const void* __restrict__ B,
                                              void* __restrict__ Cout, float* __restrict__ Rf,
                                              const void* __restrict__ bias,
                                              int M, int N, int K, const int* __restrict__ flagp) {
    int isf32 = *flagp;
    __shared__ u16 As[64][40];
    __shared__ u16 Bs[64][40];
    int tid = threadIdx.x;
    int row0 = blockIdx.x * 64, col0 = blockIdx.y * 64;
    int wave = tid >> 6, lane = tid & 63;
    int wm = (wave >> 1) * 32, wn = (wave & 1) * 32;
    int quad = lane >> 4, r = lane & 15;
    int arow = tid >> 2, akk = (tid & 3) * 8;
    int bnl = tid & 63, bkk = (tid >> 6) * 8;
    int garow = row0 + arow;
    f32x4 acc[2][2] = {};
    for (int k0 = 0; k0 < K; k0 += 32) {
        uint4 aval = {0u, 0u, 0u, 0u};
        if (garow < M) {
            if (AEXT && isf32) {
                const float* Af = (const float*)A;
                u16 t[8];
                #pragma unroll
                for (int j = 0; j < 8; ++j) t[j] = f2bf(Af[(size_t)garow * K + k0 + akk + j]);
                aval = *(uint4*)t;
            } else {
                aval = *(const uint4*)((const u16*)A + (size_t)garow * K + k0 + akk);
            }
        }
        u16 btmp[8];
        #pragma unroll
        for (int j = 0; j < 8; ++j) btmp[j] = ldbf(B, (size_t)(k0 + bkk + j) * N + col0 + bnl, isf32);
        __syncthreads();
        *(uint4*)(&As[arow][akk]) = aval;
        *(uint4*)(&Bs[bnl][bkk]) = *(uint4*)btmp;
        __syncthreads();
        bf16x8 a0 = *(const bf16x8*)(&As[wm + r][quad * 8]);
        bf16x8 a1 = *(const bf16x8*)(&As[wm + 16 + r][quad * 8]);
        bf16x8 b0 = *(const bf16x8*)(&Bs[wn + r][quad * 8]);
        bf16x8 b1 = *(const bf16x8*)(&Bs[wn + 16 + r][quad * 8]);
        acc[0][0] = __builtin_amdgcn_mfma_f32_16x16x32_bf16(a0, b0, acc[0][0], 0, 0, 0);
        acc[0][1] = __builtin_amdgcn_mfma_f32_16x16x32_bf16(a0, b1, acc[0][1], 0, 0, 0);
        acc[1][0] = __builtin_amdgcn_mfma_f32_16x16x32_bf16(a1, b0, acc[1][0], 0, 0, 0);
        acc[1][1] = __builtin_amdgcn_mfma_f32_16x16x32_bf16(a1, b1, acc[1][1], 0, 0, 0);
    }
    #pragma unroll
    for (int i = 0; i < 2; ++i)
        #pragma unroll
        for (int jn = 0; jn < 2; ++jn)
            #pragma unroll
            for (int t = 0; t < 4; ++t) {
                int grow = row0 + wm + i * 16 + quad * 4 + t;
                int gcol = col0 + wn + jn * 16 + r;
                if (grow >= M) continue;
                float v = acc[i][jn][t];
                size_t off = (size_t)grow * N + gcol;
                if (EPI == 0) {
                    ((u16*)Cout)[off] = f2bf(v);
                } else if (EPI == 2) {
                    Rf[off] += v + ldf(bias, gcol, isf32);
                } else {
                    ((float*)Cout)[off] = v + ldf(bias, gcol, isf32) + Rf[off];
                }
            }
}

// ============ FALLBACK: round-4 geglu ============
__global__ __launch_bounds__(256) void k_gemm_geglu(const u16* __restrict__ A, const void* __restrict__ B,
                                                    const void* __restrict__ bias, u16* __restrict__ Out,
                                                    int M, int Nout, int K, int ldb,
                                                    const int* __restrict__ flagp) {
    int isf32 = *flagp;
    __shared__ u16 As[64][40];
    __shared__ u16 Bs[64][40];
    int tid = threadIdx.x;
    int row0 = blockIdx.x * 64, col0 = blockIdx.y * 64;
    int wave = tid >> 6, lane = tid & 63;
    int wm = (wave >> 1) * 32, wn = (wave & 1) * 32;
    int quad = lane >> 4, r = lane & 15;
    int arow = tid >> 2, akk = (tid & 3) * 8;
    int bnl = tid & 63, bkk = (tid >> 6) * 8;
    int garow = row0 + arow;
    f32x4 acc[2][2][2] = {};
    for (int p = 0; p < 2; ++p) {
        for (int k0 = 0; k0 < K; k0 += 32) {
            uint4 aval = {0u, 0u, 0u, 0u};
            if (garow < M) aval = *(const uint4*)(A + (size_t)garow * K + k0 + akk);
            u16 btmp[8];
            #pragma unroll
            for (int j = 0; j < 8; ++j)
                btmp[j] = ldbf(B, (size_t)(k0 + bkk + j) * ldb + p * Nout + col0 + bnl, isf32);
            __syncthreads();
            *(uint4*)(&As[arow][akk]) = aval;
            *(uint4*)(&Bs[bnl][bkk]) = *(uint4*)btmp;
            __syncthreads();
            bf16x8 a0 = *(const bf16x8*)(&As[wm + r][quad * 8]);
            bf16x8 a1 = *(const bf16x8*)(&As[wm + 16 + r][quad * 8]);
            bf16x8 b0 = *(const bf16x8*)(&Bs[wn + r][quad * 8]);
            bf16x8 b1 = *(const bf16x8*)(&Bs[wn + 16 + r][quad * 8]);
            acc[p][0][0] = __builtin_amdgcn_mfma_f32_16x16x32_bf16(a0, b0, acc[p][0][0], 0, 0, 0);
            acc[p][0][1] = __builtin_amdgcn_mfma_f32_16x16x32_bf16(a0, b1, acc[p][0][1], 0, 0, 0);
            acc[p][1][0] = __builtin_amdgcn_mfma_f32_16x16x32_bf16(a1, b0, acc[p][1][0], 0, 0, 0);
            acc[p][1][1] = __builtin_amdgcn_mfma_f32_16x16x32_bf16(a1, b1, acc[p][1][1], 0, 0, 0);
        }
    }
    #pragma unroll
    for (int i = 0; i < 2; ++i)
        #pragma unroll
        for (int jn = 0; jn < 2; ++jn)
            #pragma unroll
            for (int t = 0; t < 4; ++t) {
                int grow = row0 + wm + i * 16 + quad * 4 + t;
                int gcol = col0 + wn + jn * 16 + r;
                if (grow >= M) continue;
                float a = acc[0][i][jn][t] + ldf(bias, gcol, isf32);
                float u = acc[1][i][jn][t] + ldf(bias, Nout + gcol, isf32);
                float th = tanhf(0.7978845608f * (u + 0.044715f * u * u * u));
                float gl = 0.5f * u * (1.f + th);
                Out[(size_t)grow * Nout + gcol] = f2bf(a * gl);
            }
}

// ---------------- MFMA flash attention (parameterized strides) ----------------
__global__ __launch_bounds__(256) void k_attn_flash(const u16* __restrict__ Q, const u16* __restrict__ K,
                                                    const u16* __restrict__ V, u16* __restrict__ O,
                                                    int N, int Mkv, int H, int ldq, int ldkv, int ldo) {
    __shared__ u16 Sp[4][16][40];
    __shared__ u16 VT[64][40];
    int nt = N / 64;
    int qt = blockIdx.x % nt;
    int bh = blockIdx.x / nt;
    int h = bh % H, b = bh / H;
    int tid = threadIdx.x, wave = tid >> 6, lane = tid & 63;
    int quad = lane >> 4, r = lane & 15;
    int q0 = qt * 64 + wave * 16;

    const u16* qbase = Q + ((size_t)(b * N + q0 + r)) * ldq + h * 64;
    bf16x8 aq0 = *(const bf16x8*)(qbase + quad * 8);
    bf16x8 aq1 = *(const bf16x8*)(qbase + 32 + quad * 8);

    f32x4 accO[4] = {};
    float m_i[4] = {-1e30f, -1e30f, -1e30f, -1e30f};
    float l_i[4] = {0.f, 0.f, 0.f, 0.f};

    int vkv = tid & 31, vdg = tid >> 5;

    for (int kv0 = 0; kv0 < Mkv; kv0 += 32) {
        int kr0 = min(kv0 + r, Mkv - 1);
        int kr1 = min(kv0 + 16 + r, Mkv - 1);
        const u16* kb0 = K + ((size_t)(b * Mkv + kr0)) * ldkv + h * 64;
        const u16* kb1 = K + ((size_t)(b * Mkv + kr1)) * ldkv + h * 64;
        bf16x8 bk00 = *(const bf16x8*)(kb0 + quad * 8);
        bf16x8 bk01 = *(const bf16x8*)(kb0 + 32 + quad * 8);
        bf16x8 bk10 = *(const bf16x8*)(kb1 + quad * 8);
        bf16x8 bk11 = *(const bf16x8*)(kb1 + 32 + quad * 8);
        int vrow = min(kv0 + vkv, Mkv - 1);
        uint4 vv = *(const uint4*)(V + ((size_t)(b * Mkv + vrow)) * ldkv + h * 64 + vdg * 8);

        __syncthreads();
        VT[vdg * 8 + 0][vkv] = (u16)(vv.x);
        VT[vdg * 8 + 1][vkv] = (u16)(vv.x >> 16);
        VT[vdg * 8 + 2][vkv] = (u16)(vv.y);
        VT[vdg * 8 + 3][vkv] = (u16)(vv.y >> 16);
        VT[vdg * 8 + 4][vkv] = (u16)(vv.z);
        VT[vdg * 8 + 5][vkv] = (u16)(vv.z >> 16);
        VT[vdg * 8 + 6][vkv] = (u16)(vv.w);
        VT[vdg * 8 + 7][vkv] = (u16)(vv.w >> 16);
        __syncthreads();

        f32x4 s0 = {}, s1 = {};
        s0 = __builtin_amdgcn_mfma_f32_16x16x32_bf16(aq0, bk00, s0, 0, 0, 0);
        s0 = __builtin_amdgcn_mfma_f32_16x16x32_bf16(aq1, bk01, s0, 0, 0, 0);
        s1 = __builtin_amdgcn_mfma_f32_16x16x32_bf16(aq0, bk10, s1, 0, 0, 0);
        s1 = __builtin_amdgcn_mfma_f32_16x16x32_bf16(aq1, bk11, s1, 0, 0, 0);
        bool mask0 = (kv0 + r) >= Mkv;
        bool mask1 = (kv0 + 16 + r) >= Mkv;

        #pragma unroll
        for (int t = 0; t < 4; ++t) {
            float a = mask0 ? -1e30f : s0[t] * 0.125f;
            float c = mask1 ? -1e30f : s1[t] * 0.125f;
            float mx = fmaxf(a, c);
            mx = fmaxf(mx, __shfl_xor(mx, 1));
            mx = fmaxf(mx, __shfl_xor(mx, 2));
            mx = fmaxf(mx, __shfl_xor(mx, 4));
            mx = fmaxf(mx, __shfl_xor(mx, 8));
            float mn = fmaxf(m_i[t], mx);
            float alpha = __expf(m_i[t] - mn);
            float p0 = __expf(a - mn);
            float p1 = __expf(c - mn);
            float ps = p0 + p1;
            ps += __shfl_xor(ps, 1);
            ps += __shfl_xor(ps, 2);
            ps += __shfl_xor(ps, 4);
            ps += __shfl_xor(ps, 8);
            l_i[t] = l_i[t] * alpha + ps;
            m_i[t] = mn;
            accO[0][t] *= alpha; accO[1][t] *= alpha; accO[2][t] *= alpha; accO[3][t] *= alpha;
            Sp[wave][quad * 4 + t][r] = f2bf(p0);
            Sp[wave][quad * 4 + t][16 + r] = f2bf(p1);
        }

        bf16x8 ap = *(const bf16x8*)(&Sp[wave][r][quad * 8]);
        #pragma unroll
        for (int g = 0; g < 4; ++g) {
            bf16x8 bvv = *(const bf16x8*)(&VT[g * 16 + r][quad * 8]);
            accO[g] = __builtin_amdgcn_mfma_f32_16x16x32_bf16(ap, bvv, accO[g], 0, 0, 0);
        }
    }

    u16* ob = O + ((size_t)(b * N + q0)) * ldo + h * 64;
    #pragma unroll
    for (int t = 0; t < 4; ++t) {
        float inv = 1.f / l_i[t];
        #pragma unroll
        for (int g = 0; g < 4; ++g)
            ob[(size_t)(quad * 4 + t) * ldo + g * 16 + r] = f2bf(accO[g][t] * inv);
    }
}

extern "C" void kernel_launch(void* const* d_in, const int* in_sizes, int n_in,
                              void* d_out, int out_size, void* d_ws, size_t ws_size,
                              hipStream_t stream) {
    const void* x    = d_in[0];
    const void* ctx  = d_in[1];
    const void* g1   = d_in[2];
    const void* be1  = d_in[3];
    const void* wq1  = d_in[4];
    const void* wk1  = d_in[5];
    const void* wv1  = d_in[6];
    const void* wo1  = d_in[7];
    const void* bo1  = d_in[8];
    const void* g2   = d_in[9];
    const void* be2  = d_in[10];
    const void* wq2  = d_in[11];
    const void* wk2  = d_in[12];
    const void* wv2  = d_in[13];
    const void* wo2  = d_in[14];
    const void* bo2  = d_in[15];
    const void* g3   = d_in[16];
    const void* be3  = d_in[17];
    const void* wff1 = d_in[18];
    const void* bff1 = d_in[19];
    const void* wff2 = d_in[20];
    const void* bff2 = d_in[21];

    const int BT = 4096, D = 1280;
    dim3 blk(256);
    char* ws = (char*)d_ws;

    const size_t NEED_FAST = 117393664;
    if (ws_size >= NEED_FAST) {
        // ---------- fast path ----------
        int*   flag   = (int*)(ws);
        u16* lnout    = (u16*)(ws + 256);            // 4096x1280 bf16
        u16* qkv      = (u16*)(ws + 10486016);       // 4096x3840 bf16 (region R)
        u16* attnout  = (u16*)(ws + 10486016 + 31457280);
        u16* gbuf     = (u16*)(ws + 10486016);       // 4096x5120 bf16, aliases qkv+attnout
        u16* ctxb     = (u16*)(ws + 52429056);       // 308x768 bf16
        u16* kv2      = (u16*)(ws + 52902144);       // 308x2560 bf16
        u16* wqkv1t   = (u16*)(ws + 54479104);       // [3840][1280]
        u16* wo1t     = (u16*)(ws + 64309504);       // [1280][1280]
        u16* wq2t     = (u16*)(ws + 67586304);
        u16* wkv2t    = (u16*)(ws + 70863104);       // [2560][768]
        u16* wo2t     = (u16*)(ws + 74795264);
        u16* wff1t    = (u16*)(ws + 78072064);       // [10240][1280]
        u16* wff2t    = (u16*)(ws + 104286464);      // [1280][5120]
        float* pff2   = (float*)(ws + 54479104);     // FF2 split-K partial (21 MB); at FF2 time the
                                                     // wqkv1t/wo1t/... weights are dead (re-transposed
                                                     // each launch)
        float* pWO    = (float*)(ws + 10486016);     // WO1/WO2 split-K partial (21 MB) in the qkv
                                                     // region: dead after each attention, re-written
                                                     // by the next q/gbuf producer AFTER the LN fold
        float* xres   = (float*)d_out;               // residual lives in the fp32 output

        k_detect<<<dim3(1), blk, 0, stream>>>((const u16*)x, flag);
        k_b2f<<<dim3((BT * D + 255) / 256), blk, 0, stream>>>(x, xres, BT * D, flag);
        // weight transposes (batched: 10 -> 5 launches)
        k_transpose3<<<dim3(40, 40, 3), blk, 0, stream>>>(wq1, wk1, wv1,
                                                          wqkv1t, wqkv1t + 1280 * 1280,
                                                          wqkv1t + 2 * 1280 * 1280, 1280, 1280, flag);
        k_transpose3<<<dim3(40, 40, 3), blk, 0, stream>>>(wo1, wq2, wo2,
                                                          wo1t, wq2t, wo2t, 1280, 1280, flag);
        k_transpose3<<<dim3(24, 40, 2), blk, 0, stream>>>(wk2, wv2, wv2,
                                                          wkv2t, wkv2t + 1280 * 768,
                                                          wkv2t + 1280 * 768, 768, 1280, flag);
        k_transpose<<<dim3(40, 320), blk, 0, stream>>>(wff1, wff1t, 1280, 10240, flag);
        k_transpose<<<dim3(160, 40), blk, 0, stream>>>(wff2, wff2t, 5120, 1280, flag);
        k_cvt<<<dim3((308 * 768 + 255) / 256), blk, 0, stream>>>(ctx, ctxb, 308 * 768, flag);
        // --- self attention ---
        k_layernorm<<<dim3(BT), blk, 0, stream>>>(xres, nullptr, g1, be1, lnout, D, flag);
        k_gemm8<0><<<dim3(16, 15), dim3(512), 0, stream>>>(lnout, wqkv1t, qkv, nullptr, BT, 3840, D, flag);
        k_attn_flash<<<dim3(16 * 80), blk, 0, stream>>>(qkv, qkv + 1280, qkv + 2560, attnout,
                                                        1024, 1024, 20, 3840, 3840, 1280);
        // WO1: split-K=2; kz1 partial -> pWO (qkv region now dead); folded by LN2
        k_gemm_t<2><<<dim3(32, 10, 2), blk, 0, stream>>>(attnout, wo1t, pWO, xres, bo1, BT, D, D, flag);
        // --- cross attention ---
        k_layernorm<<<dim3(BT), blk, 0, stream>>>(xres, pWO, g2, be2, lnout, D, flag);
        k_gemm_t<0><<<dim3(32, 10), blk, 0, stream>>>(lnout, wq2t, qkv, nullptr, nullptr, BT, D, D, flag);
        k_gemm_t<0><<<dim3(3, 20), blk, 0, stream>>>(ctxb, wkv2t, kv2, nullptr, nullptr, 308, 2560, 768, flag);
        k_attn_flash<<<dim3(16 * 80), blk, 0, stream>>>(qkv, kv2, kv2 + 1280, attnout,
                                                        1024, 77, 20, 1280, 2560, 1280);
        // WO2: split-K=2; kz1 partial -> pWO (qkv dead again); folded by LN3
        k_gemm_t<2><<<dim3(32, 10, 2), blk, 0, stream>>>(attnout, wo2t, pWO, xres, bo2, BT, D, D, flag);
        // --- GEGLU FF ---
        k_layernorm<<<dim3(BT), blk, 0, stream>>>(xres, pWO, g3, be3, lnout, D, flag);
        k_gemm8<1><<<dim3(16, 40), dim3(512), 0, stream>>>(lnout, wff1t, gbuf, bff1, BT, 10240, D, flag);
        // FF2: split-K=2; kz1 partial -> pff2; fold with k_addp (final output, no following LN)
        k_gemm_t<2><<<dim3(32, 10, 2), blk, 0, stream>>>(gbuf, wff2t, pff2, xres, bff2, BT, D, 5120, flag);
        k_addp<<<dim3(2048), blk, 0, stream>>>(xres, pff2, BT * D / 4);
    } else {
        // ---------- fallback: round-4 path (known-good, ~75 MB ws) ----------
        int*   flag    = (int*)(ws);
        float* xres    = (float*)(ws + 256);
        u16* lnout     = (u16*)(ws + 20971776);
        u16* q         = (u16*)(ws + 31457536);
        u16* kbuf      = (u16*)(ws + 41943296);
        u16* vbuf      = (u16*)(ws + 52429056);
        u16* attnout   = (u16*)(ws + 62914816);
        u16* k2        = (u16*)(ws + 73400576);
        u16* v2        = (u16*)(ws + 74189056);
        u16* gbuf      = (u16*)(ws + 31457536);

        dim3 g_gemm(64, 20);
        dim3 g_kv(5, 20);
        dim3 g_attn(16 * 80);

        k_detect<<<dim3(1), blk, 0, stream>>>((const u16*)x, flag);
        k_b2f<<<dim3((BT * D + 255) / 256), blk, 0, stream>>>(x, xres, BT * D, flag);
        k_layernorm<<<dim3(BT), blk, 0, stream>>>(xres, nullptr, g1, be1, lnout, D, flag);
        k_gemm<0, false><<<g_gemm, blk, 0, stream>>>(lnout, wq1, q, nullptr, nullptr, BT, D, D, flag);
        k_gemm<0, false><<<g_gemm, blk, 0, stream>>>(lnout, wk1, kbuf, nullptr, nullptr, BT, D, D, flag);
        k_gemm<0, false><<<g_gemm, blk, 0, stream>>>(lnout, wv1, vbuf, nullptr, nullptr, BT, D, D, flag);
        k_attn_flash<<<g_attn, blk, 0, stream>>>(q, kbuf, vbuf, attnout, 1024, 1024, 20, 1280, 1280, 1280);
        k_gemm<2, false><<<g_gemm, blk, 0, stream>>>(attnout, wo1, nullptr, xres, bo1, BT, D, D, flag);
        k_layernorm<<<dim3(BT), blk, 0, stream>>>(xres, nullptr, g2, be2, lnout, D, flag);
        k_gemm<0, false><<<g_gemm, blk, 0, stream>>>(lnout, wq2, q, nullptr, nullptr, BT, D, D, flag);
        k_gemm<0, true><<<g_kv, blk, 0, stream>>>(ctx, wk2, k2, nullptr, nullptr, 308, D, 768, flag);
        k_gemm<0, true><<<g_kv, blk, 0, stream>>>(ctx, wv2, v2, nullptr, nullptr, 308, D, 768, flag);
        k_attn_flash<<<g_attn, blk, 0, stream>>>(q, k2, v2, attnout, 1024, 77, 20, 1280, 1280, 1280);
        k_gemm<2, false><<<g_gemm, blk, 0, stream>>>(attnout, wo2, nullptr, xres, bo2, BT, D, D, flag);
        k_layernorm<<<dim3(BT), blk, 0, stream>>>(xres, nullptr, g3, be3, lnout, D, flag);
        k_gemm_geglu<<<dim3(64, 80), blk, 0, stream>>>(lnout, wff1, bff1, gbuf, BT, 5120, D, 10240, flag);
        k_gemm<3, false><<<g_gemm, blk, 0, stream>>>(gbuf, wff2, d_out, xres, bff2, BT, D, 5120, flag);
    }
}

// Round 9
// 831.077 us; speedup vs baseline: 1.0126x; 1.0003x over previous
//
#include <hip/hip_runtime.h>

typedef unsigned short u16;
typedef __bf16 bf16x8 __attribute__((ext_vector_type(8)));
typedef float f32x4 __attribute__((ext_vector_type(4)));

static __device__ __forceinline__ float bf2f(u16 u) {
    union { unsigned int i; float f; } v; v.i = ((unsigned int)u) << 16; return v.f;
}
static __device__ __forceinline__ u16 f2bf(float f) {
    union { float f; unsigned int i; } v; v.f = f;
    unsigned int b = v.i;
    b += 0x7fffu + ((b >> 16) & 1u);   // RNE
    return (u16)(b >> 16);
}
static __device__ __forceinline__ u16 ldbf(const void* p, size_t i, int isf32) {
    return isf32 ? f2bf(((const float*)p)[i]) : ((const u16*)p)[i];
}
static __device__ __forceinline__ float ldf(const void* p, size_t i, int isf32) {
    return isf32 ? ((const float*)p)[i] : bf2f(((const u16*)p)[i]);
}
// async global->LDS, 16B per lane; lds dest = wave-uniform base + lane*16 (m97/m104)
static __device__ __forceinline__ void glds16(const u16* g, u16* l) {
    __builtin_amdgcn_global_load_lds(
        (const __attribute__((address_space(1))) unsigned int*)g,
        (__attribute__((address_space(3))) unsigned int*)l,
        16, 0, 0);
}
// XCD-chunked bijective remap (T1, m192). Used ONLY for k_gemm8.
static __device__ __forceinline__ int xcd_swz(int lid, int nwg) {
    return ((nwg & 7) == 0) ? ((lid & 7) * (nwg >> 3) + (lid >> 3)) : lid;
}

// ---------------- dtype detector (insurance; inputs measured fp32) ----------------
__global__ __launch_bounds__(256) void k_detect(const u16* __restrict__ xu, int* __restrict__ flag) {
    u16 v = xu[threadIdx.x * 2];
    int e = (v >> 7) & 0xFF;
    int sane = (e >= 87 && e <= 133) ? 1 : 0;
    int total = __syncthreads_count(sane);
    if (threadIdx.x == 0) flag[0] = (total < 192) ? 1 : 0;
}

// ---------------- x -> f32 residual stream ----------------
__global__ __launch_bounds__(256) void k_b2f(const void* __restrict__ in, float* __restrict__ out, int n,
                                             const int* __restrict__ flagp) {
    int isf32 = *flagp;
    int i = blockIdx.x * 256 + threadIdx.x;
    if (i < n) out[i] = ldf(in, i, isf32);
}

// ---------------- external -> bf16 convert ----------------
__global__ __launch_bounds__(256) void k_cvt(const void* __restrict__ in, u16* __restrict__ out, int n,
                                             const int* __restrict__ flagp) {
    int isf32 = *flagp;
    int i = blockIdx.x * 256 + threadIdx.x;
    if (i < n) out[i] = ldbf(in, i, isf32);
}

// ---------------- split-K reduce: X += P (fp32, vectorized) ----------------
__global__ __launch_bounds__(256) void k_addp(float* __restrict__ X, const float* __restrict__ P, int n4) {
    int i = blockIdx.x * 256 + threadIdx.x;
    int stride = gridDim.x * 256;
    for (; i < n4; i += stride) {
        f32x4 a = ((const f32x4*)X)[i];
        f32x4 b = ((const f32x4*)P)[i];
        a[0] += b[0]; a[1] += b[1]; a[2] += b[2]; a[3] += b[3];
        ((f32x4*)X)[i] = a;
    }
}

// ---------------- weight transpose+convert: W[K,N] (ext) -> Wt[N,K] bf16 ----------------
__global__ __launch_bounds__(256) void k_transpose(const void* __restrict__ W, u16* __restrict__ Wt,
                                                   int K, int N, const int* __restrict__ flagp) {
    int isf32 = *flagp;
    __shared__ u16 T[32][33];
    int k0 = blockIdx.x * 32, n0 = blockIdx.y * 32;
    int tid = threadIdx.x;
    int c = tid & 31, rr = tid >> 5;
    #pragma unroll
    for (int j = 0; j < 4; ++j) {
        int k = rr + j * 8;
        T[k][c] = ldbf(W, (size_t)(k0 + k) * N + n0 + c, isf32);
    }
    __syncthreads();
    #pragma unroll
    for (int j = 0; j < 4; ++j) {
        int n = rr + j * 8;
        Wt[(size_t)(n0 + n) * K + k0 + c] = T[c][n];
    }
}

// ---------------- batched transpose: up to 3 same-shape weights in one launch ----------------
__global__ __launch_bounds__(256) void k_transpose3(const void* __restrict__ W0, const void* __restrict__ W1,
                                                    const void* __restrict__ W2,
                                                    u16* __restrict__ D0, u16* __restrict__ D1,
                                                    u16* __restrict__ D2,
                                                    int K, int N, const int* __restrict__ flagp) {
    int isf32 = *flagp;
    int z = blockIdx.z;
    const void* W = (z == 0) ? W0 : (z == 1) ? W1 : W2;
    u16* Wt = (z == 0) ? D0 : (z == 1) ? D1 : D2;
    __shared__ u16 T[32][33];
    int k0 = blockIdx.x * 32, n0 = blockIdx.y * 32;
    int tid = threadIdx.x;
    int c = tid & 31, rr = tid >> 5;
    #pragma unroll
    for (int j = 0; j < 4; ++j) {
        int k = rr + j * 8;
        T[k][c] = ldbf(W, (size_t)(k0 + k) * N + n0 + c, isf32);
    }
    __syncthreads();
    #pragma unroll
    for (int j = 0; j < 4; ++j) {
        int n = rr + j * 8;
        Wt[(size_t)(n0 + n) * K + k0 + c] = T[c][n];
    }
}

// ---------------- LayerNorm: fp32 in -> bf16 out; optional split-K partial fold ----------------
// If P != null: x[i] += P[i] first (residual write-back), then normalize the summed value.
__global__ __launch_bounds__(256) void k_layernorm(float* __restrict__ X, const float* __restrict__ P,
                                                   const void* __restrict__ G, const void* __restrict__ Bb,
                                                   u16* __restrict__ Y, int D,
                                                   const int* __restrict__ flagp) {
    int isf32 = *flagp;
    int row = blockIdx.x;
    float* xr = X + (size_t)row * D;
    const float* pr = P ? (P + (size_t)row * D) : nullptr;
    float s = 0.f, s2 = 0.f;
    for (int i = threadIdx.x; i < D; i += 256) {
        float v = xr[i] + (P ? pr[i] : 0.f);
        s += v; s2 += v * v;
    }
    #pragma unroll
    for (int off = 32; off; off >>= 1) { s += __shfl_down(s, off); s2 += __shfl_down(s2, off); }
    __shared__ float rs[4], rs2[4];
    __shared__ float stat[2];
    int w = threadIdx.x >> 6;
    if ((threadIdx.x & 63) == 0) { rs[w] = s; rs2[w] = s2; }
    __syncthreads();
    if (threadIdx.x == 0) {
        float ts = rs[0] + rs[1] + rs[2] + rs[3];
        float ts2 = rs2[0] + rs2[1] + rs2[2] + rs2[3];
        float mu = ts / D;
        float var = ts2 / D - mu * mu;
        stat[0] = mu; stat[1] = rsqrtf(var + 1e-5f);
    }
    __syncthreads();
    float mu = stat[0], rstd = stat[1];
    u16* yr = Y + (size_t)row * D;
    for (int i = threadIdx.x; i < D; i += 256) {
        float v = xr[i] + (P ? pr[i] : 0.f);
        if (P) xr[i] = v;                      // residual stream now holds the full sum
        yr[i] = f2bf((v - mu) * rstd * ldf(G, i, isf32) + ldf(Bb, i, isf32));
    }
}

// ============ 256x256 GEMM, overlapped 4-phase schedule (T1..T5 + counted-lgkm) ============
// (parked at ~135 us; three schedule variants measured identical)
template <int EPI>
__global__ __launch_bounds__(512, 2) void k_gemm8(const u16* __restrict__ A, const u16* __restrict__ Bt,
                                                  void* __restrict__ Cout, const void* __restrict__ bias,
                                                  int M, int N, int K, const int* __restrict__ flagp) {
    __shared__ __align__(16) u16 sm[65536];   // 128 KiB static
    const int tid = threadIdx.x;
    const int w = tid >> 6;
    const int lane = tid & 63;
    const int quad = lane >> 4, r = lane & 15;
    const int wm = w >> 2, wn = w & 3;          // 2 x 4 wave grid
    const int lid = blockIdx.x + blockIdx.y * gridDim.x;
    const int nid = xcd_swz(lid, gridDim.x * gridDim.y);
    const int row0 = (nid % gridDim.x) * 256;
    const int col0 = (nid / gridDim.x) * 256;
    const int NT = K >> 6;

    const u16* aP[2][2];
    const u16* bP[2][2];
    #pragma unroll
    for (int j = 0; j < 2; ++j) {
        int c = tid + w * 64 + j * 64;          // = w*128 + j*64 + lane
        int rj = c >> 3;                        // row within half (0..127)
        int qe = (c & 7) ^ (rj & 7);            // inverse-swizzled global chunk
        #pragma unroll
        for (int h = 0; h < 2; ++h) {
            int gr = h * 128 + rj;
            aP[h][j] = A + (size_t)(row0 + gr) * K + qe * 8;
            int n = col0 + gr;
            int m = (EPI == 1) ? (((n >> 4) & 1) * 5120 + (n >> 5) * 16 + (n & 15)) : n;
            bP[h][j] = Bt + (size_t)m * K + qe * 8;
        }
    }
    auto stageA = [&](int h, int t) {
        u16* base = sm + (t & 1) * 32768 + h * 8192 + w * 1024;
        glds16(aP[h][0] + t * 64, base);
        glds16(aP[h][1] + t * 64, base + 512);
    };
    auto stageB = [&](int h, int t) {
        u16* base = sm + (t & 1) * 32768 + 16384 + h * 8192 + w * 1024;
        glds16(bP[h][0] + t * 64, base);
        glds16(bP[h][1] + t * 64, base + 512);
    };

    f32x4 acc[2][2][4][2] = {};
    const int xq = r & 7;
    bf16x8 afA[4][2], afB[4][2], bf0[2][2], bf1[2][2];

    auto readA = [&](bf16x8 (&dst)[4][2], int Ab, int half) {
        #pragma unroll
        for (int i = 0; i < 4; ++i) {
            int ar = half * 128 + wm * 64 + i * 16 + r;
            #pragma unroll
            for (int ks = 0; ks < 2; ++ks)
                dst[i][ks] = *(const bf16x8*)(sm + Ab + ar * 64 + (((ks * 4 + quad) ^ xq) * 8));
        }
    };
    auto readB = [&](bf16x8 (&dst)[2][2], int Bb, int half) {
        #pragma unroll
        for (int g = 0; g < 2; ++g) {
            int br = half * 128 + wn * 32 + g * 16 + r;
            #pragma unroll
            for (int ks = 0; ks < 2; ++ks)
                dst[g][ks] = *(const bf16x8*)(sm + Bb + br * 64 + (((ks * 4 + quad) ^ xq) * 8));
        }
    };
    auto domfma = [&](int qm, int qn, bf16x8 (&a)[4][2], bf16x8 (&b)[2][2]) {
        #pragma unroll
        for (int ks = 0; ks < 2; ++ks)
            #pragma unroll
            for (int i = 0; i < 4; ++i)
                #pragma unroll
                for (int g = 0; g < 2; ++g)
                    acc[qm][qn][i][g] = __builtin_amdgcn_mfma_f32_16x16x32_bf16(
                        a[i][ks], b[g][ks], acc[qm][qn][i][g], 0, 0, 0);
    };

    // prologue: tile 0 complete + halves0 of tile 1; vmcnt(4) -> tile 0 landed
    stageA(0, 0); stageB(0, 0); stageA(1, 0); stageB(1, 0);
    if (NT > 1) {
        stageA(0, 1); stageB(0, 1);
        asm volatile("s_waitcnt vmcnt(4)" ::: "memory");
    } else {
        asm volatile("s_waitcnt vmcnt(0)" ::: "memory");
    }
    __builtin_amdgcn_s_barrier();
    readA(afA, 0, 0);
    readB(bf0, 16384, 0);

    for (int t = 0; t < NT; ++t) {
        const int Ab = (t & 1) * 32768;
        const int Bb = Ab + 16384;
        const int Abn = ((t + 1) & 1) * 32768;
        // ---- ph0: MFMA(afA,bf0); prefetch bf1 under it ----
        readB(bf1, Bb, 1);
        __builtin_amdgcn_sched_barrier(0);
        __builtin_amdgcn_s_setprio(1);
        domfma(0, 0, afA, bf0);
        __builtin_amdgcn_s_setprio(0);
        if (t + 1 < NT) stageA(1, t + 1);
        __builtin_amdgcn_s_barrier();
        // ---- ph1: MFMA(afA,bf1); prefetch afB under it ----
        readA(afB, Ab, 1);
        __builtin_amdgcn_sched_barrier(0);
        __builtin_amdgcn_s_setprio(1);
        domfma(0, 1, afA, bf1);
        __builtin_amdgcn_s_setprio(0);
        if (t + 1 < NT) stageB(1, t + 1);
        __builtin_amdgcn_s_barrier();
        // ---- ph2: MFMA(afB,bf1) ----
        __builtin_amdgcn_s_setprio(1);
        domfma(1, 1, afB, bf1);
        __builtin_amdgcn_s_setprio(0);
        if (t + 2 < NT) stageA(0, t + 2);
        __builtin_amdgcn_s_barrier();
        // ---- ph3: MFMA(afB,bf0); vmcnt-gate + next-tile frag issue ----
        __builtin_amdgcn_s_setprio(1);
        domfma(1, 0, afB, bf0);
        __builtin_amdgcn_s_setprio(0);
        if (t + 2 < NT) stageB(0, t + 2);
        if (t + 2 < NT) asm volatile("s_waitcnt vmcnt(4)" ::: "memory");
        else            asm volatile("s_waitcnt vmcnt(0)" ::: "memory");
        __builtin_amdgcn_s_barrier();
        if (t + 1 < NT) {
            readA(afA, Abn, 0);
            readB(bf0, Abn + 16384, 0);
        }
    }

    if (EPI == 0) {
        u16* C = (u16*)Cout;
        #pragma unroll
        for (int qm = 0; qm < 2; ++qm) {
            #pragma unroll
            for (int qn = 0; qn < 2; ++qn) {
                #pragma unroll
                for (int i = 0; i < 4; ++i) {
                    int grow = row0 + qm * 128 + wm * 64 + i * 16 + quad * 4;
                    #pragma unroll
                    for (int g = 0; g < 2; ++g) {
                        int gcol = col0 + qn * 128 + wn * 32 + g * 16 + r;
                        #pragma unroll
                        for (int t4 = 0; t4 < 4; ++t4)
                            C[(size_t)(grow + t4) * N + gcol] = f2bf(acc[qm][qn][i][g][t4]);
                    }
                }
            }
        }
    } else {
        const int isf32 = *flagp;
        u16* C = (u16*)Cout;  // [M][5120]
        #pragma unroll
        for (int qm = 0; qm < 2; ++qm) {
            #pragma unroll
            for (int qn = 0; qn < 2; ++qn) {
                int ncb = col0 + qn * 128 + wn * 32;
                int oc = (ncb >> 1) + r;
                float bva = ldf(bias, oc, isf32);
                float bvu = ldf(bias, 5120 + oc, isf32);
                #pragma unroll
                for (int i = 0; i < 4; ++i) {
                    int grow = row0 + qm * 128 + wm * 64 + i * 16 + quad * 4;
                    #pragma unroll
                    for (int t4 = 0; t4 < 4; ++t4) {
                        float a = acc[qm][qn][i][0][t4] + bva;
                        float u = acc[qm][qn][i][1][t4] + bvu;
                        float z2 = 1.5957691216f * (u + 0.044715f * u * u * u);
                        float gl = u * __builtin_amdgcn_rcpf(1.f + __expf(-z2));
                        C[(size_t)(grow + t4) * 5120 + oc] = f2bf(a * gl);
                    }
                }
            }
        }
    }
}

// ============ FAST PATH: 128x128 tile GEMM via global_load_lds, xor-swizzled LDS ============
// EPI: 0 = bf16 store; 2 = xres += acc + bias (fp32). Split-K (gridDim.z==2):
// kz=0 -> xres += acc + bias (non-atomic, sole owner); kz=1 -> fp32 partial into Cout;
// the partial is folded by k_addp or by the following k_layernorm(P=partial).
template <int EPI>
__global__ __launch_bounds__(256) void k_gemm_t(const u16* __restrict__ A, const u16* __restrict__ Bt,
                                                void* __restrict__ Cout, float* __restrict__ Rf,
                                                const void* __restrict__ bias,
                                                int M, int N, int K, const int* __restrict__ flagp) {
    int isf32 = *flagp;
    __shared__ __align__(16) u16 As[4096];
    __shared__ __align__(16) u16 Bs[4096];
    int tid = threadIdx.x;
    int row0 = blockIdx.x * 128, col0 = blockIdx.y * 128;
    int S = gridDim.z, kz = blockIdx.z;
    int kseg = K / S;
    int kb = kz * kseg, ke = kb + kseg;
    int wave = tid >> 6, lane = tid & 63;
    int wm = (wave >> 1) * 64, wn = (wave & 1) * 64;
    int quad = lane >> 4, r = lane & 15;
    int c0 = wave * 64 + lane, c1 = 256 + c0;
    int ar0 = c0 >> 2, aq0 = (c0 & 3) ^ ((ar0 >> 1) & 3);
    int ar1 = c1 >> 2, aq1 = (c1 & 3) ^ ((ar1 >> 1) & 3);
    const u16* Ag0 = A + (size_t)min(row0 + ar0, M - 1) * K + aq0 * 8;
    const u16* Ag1 = A + (size_t)min(row0 + ar1, M - 1) * K + aq1 * 8;
    const u16* Bg0 = Bt + (size_t)(col0 + ar0) * K + aq0 * 8;
    const u16* Bg1 = Bt + (size_t)(col0 + ar1) * K + aq1 * 8;
    u16* lA0 = As + wave * 512;
    u16* lA1 = As + 2048 + wave * 512;
    u16* lB0 = Bs + wave * 512;
    u16* lB1 = Bs + 2048 + wave * 512;
    f32x4 acc[4][4] = {};
    for (int k0 = kb; k0 < ke; k0 += 32) {
        __syncthreads();
        glds16(Ag0 + k0, lA0);
        glds16(Ag1 + k0, lA1);
        glds16(Bg0 + k0, lB0);
        glds16(Bg1 + k0, lB1);
        __syncthreads();
        bf16x8 af[4], bfv[4];
        #pragma unroll
        for (int i = 0; i < 4; ++i) {
            int row = wm + i * 16 + r;
            af[i] = *(const bf16x8*)(As + (row * 4 + (quad ^ ((row >> 1) & 3))) * 8);
        }
        #pragma unroll
        for (int g = 0; g < 4; ++g) {
            int row = wn + g * 16 + r;
            bfv[g] = *(const bf16x8*)(Bs + (row * 4 + (quad ^ ((row >> 1) & 3))) * 8);
        }
        #pragma unroll
        for (int i = 0; i < 4; ++i)
            #pragma unroll
            for (int g = 0; g < 4; ++g)
                acc[i][g] = __builtin_amdgcn_mfma_f32_16x16x32_bf16(af[i], bfv[g], acc[i][g], 0, 0, 0);
    }
    #pragma unroll
    for (int i = 0; i < 4; ++i) {
        int grow = row0 + wm + i * 16 + quad * 4;
        if (grow >= M) continue;
        #pragma unroll
        for (int g = 0; g < 4; ++g) {
            int gcol = col0 + wn + g * 16 + r;
            float bv = (EPI == 2 && kz == 0) ? ldf(bias, gcol, isf32) : 0.f;
            #pragma unroll
            for (int t = 0; t < 4; ++t) {
                float v = acc[i][g][t];
                size_t off = (size_t)(grow + t) * N + gcol;
                if (EPI == 0) {
                    ((u16*)Cout)[off] = f2bf(v);
                } else {
                    if (kz == 0) Rf[off] += v + bv;          // sole owner of this element in z=0
                    else         ((float*)Cout)[off] = v;    // partial; folded later
                }
            }
        }
    }
}

// ============ FAST PATH: GEGLU ff1 via global_load_lds; Nout=5120 (fallback for gemm8) ====
__global__ __launch_bounds__(256) void k_geglu_t(const u16* __restrict__ A, const u16* __restrict__ Bt,
                                                 const void* __restrict__ bias, u16* __restrict__ Out,
                                                 int M, int K, const int* __restrict__ flagp) {
    const int Nout = 5120;
    int isf32 = *flagp;
    __shared__ __align__(16) u16 As[4096];
    __shared__ __align__(16) u16 Bs[4096];
    int tid = threadIdx.x;
    int row0 = blockIdx.x * 128, col0 = blockIdx.y * 64;
    int wave = tid >> 6, lane = tid & 63;
    int quad = lane >> 4, r = lane & 15;
    int c0 = wave * 64 + lane, c1 = 256 + c0;
    int ar0 = c0 >> 2, aq0 = (c0 & 3) ^ ((ar0 >> 1) & 3);
    int ar1 = c1 >> 2, aq1 = (c1 & 3) ^ ((ar1 >> 1) & 3);
    const u16* Ag0 = A + (size_t)min(row0 + ar0, M - 1) * K + aq0 * 8;
    const u16* Ag1 = A + (size_t)min(row0 + ar1, M - 1) * K + aq1 * 8;
    const u16* Bg0 = Bt + (size_t)((ar0 >> 6) * Nout + col0 + (ar0 & 63)) * K + aq0 * 8;
    const u16* Bg1 = Bt + (size_t)((ar1 >> 6) * Nout + col0 + (ar1 & 63)) * K + aq1 * 8;
    u16* lA0 = As + wave * 512;
    u16* lA1 = As + 2048 + wave * 512;
    u16* lB0 = Bs + wave * 512;
    u16* lB1 = Bs + 2048 + wave * 512;
    f32x4 acc[2][2][4] = {};
    for (int k0 = 0; k0 < K; k0 += 32) {
        __syncthreads();
        glds16(Ag0 + k0, lA0);
        glds16(Ag1 + k0, lA1);
        glds16(Bg0 + k0, lB0);
        glds16(Bg1 + k0, lB1);
        __syncthreads();
        bf16x8 af[2], bv[2][4];
        #pragma unroll
        for (int i = 0; i < 2; ++i) {
            int row = wave * 32 + i * 16 + r;
            af[i] = *(const bf16x8*)(As + (row * 4 + (quad ^ ((row >> 1) & 3))) * 8);
        }
        #pragma unroll
        for (int p = 0; p < 2; ++p)
            #pragma unroll
            for (int g = 0; g < 4; ++g) {
                int row = p * 64 + g * 16 + r;
                bv[p][g] = *(const bf16x8*)(Bs + (row * 4 + (quad ^ ((row >> 1) & 3))) * 8);
            }
        #pragma unroll
        for (int p = 0; p < 2; ++p)
            #pragma unroll
            for (int i = 0; i < 2; ++i)
                #pragma unroll
                for (int g = 0; g < 4; ++g)
                    acc[p][i][g] = __builtin_amdgcn_mfma_f32_16x16x32_bf16(af[i], bv[p][g], acc[p][i][g], 0, 0, 0);
    }
    #pragma unroll
    for (int i = 0; i < 2; ++i) {
        int grow = row0 + wave * 32 + i * 16 + quad * 4;
        #pragma unroll
        for (int g = 0; g < 4; ++g) {
            int gcol = col0 + g * 16 + r;
            float bva = ldf(bias, gcol, isf32);
            float bvu = ldf(bias, Nout + gcol, isf32);
            #pragma unroll
            for (int t = 0; t < 4; ++t) {
                float a = acc[0][i][g][t] + bva;
                float u = acc[1][i][g][t] + bvu;
                float z2 = 1.5957691216f * (u + 0.044715f * u * u * u);
                float gl = u * __builtin_amdgcn_rcpf(1.f + __expf(-z2));
                Out[(size_t)(grow + t) * Nout + gcol] = f2bf(a * gl);
            }
        }
    }
}

// ============ FALLBACK: round-4 64x64 GEMM (known-good) ============
template <int EPI, bool AEXT>
__global__ __launch_bounds__(256) void k_gemm(const void* __restrict__ A, const void* __restrict__ B,
                                              void* __restrict__ Cout, float* __restrict__ Rf,
                                              const void* __restrict__ bias,
                                              int M, int N, int K, const int* __restrict__ flagp) {
    int isf32 = *flagp;
    __shared__ u16 As[64][40];
    __shared__ u16 Bs[64][40];
    int tid = threadIdx.x;
    int row0 = blockIdx.x * 64, col0 = blockIdx.y * 64;
    int wave = tid >> 6, lane = tid & 63;
    int wm = (wave >> 1) * 32, wn = (wave & 1) * 32;
    int quad = lane >> 4, r = lane & 15;
    int arow = tid >> 2, akk = (tid & 3) * 8;
    int bnl = tid & 63, bkk = (tid >> 6) * 8;
    int garow = row0 + arow;
    f32x4 acc[2][2] = {};
    for (int k0 = 0; k0 < K; k0 += 32) {
        uint4 aval = {0u, 0u, 0u, 0u};
        if (garow < M) {
            if (AEXT && isf32) {
                const float* Af = (const float*)A;
                u16 t[8];
                #pragma unroll
                for (int j = 0; j < 8; ++j) t[j] = f2bf(Af[(size_t)garow * K + k0 + akk + j]);
                aval = *(uint4*)t;
            } else {
                aval = *(const uint4*)((const u16*)A + (size_t)garow * K + k0 + akk);
            }
        }
        u16 btmp[8];
        #pragma unroll
        for (int j = 0; j < 8; ++j) btmp[j] = ldbf(B, (size_t)(k0 + bkk + j) * N + col0 + bnl, isf32);
        __syncthreads();
        *(uint4*)(&As[arow][akk]) = aval;
        *(uint4*)(&Bs[bnl][bkk]) = *(uint4*)btmp;
        __syncthreads();
        bf16x8 a0 = *(const bf16x8*)(&As[wm + r][quad * 8]);
        bf16x8 a1 = *(const bf16x8*)(&As[wm + 16 + r][quad * 8]);
        bf16x8 b0 = *(const bf16x8*)(&Bs[wn + r][quad * 8]);
        bf16x8 b1 = *(const bf16x8*)(&Bs[wn + 16 + r][quad * 8]);
        acc[0][0] = __builtin_amdgcn_mfma_f32_16x16x32_bf16(a0, b0, acc[0][0], 0, 0, 0);
        acc[0][1] = __builtin_amdgcn_mfma_f32_16x16x32_bf16(a0, b1, acc[0][1], 0, 0, 0);
        acc[1][0] = __builtin_amdgcn_mfma_f32_16x16x32_bf16(a1, b0, acc[1][0], 0, 0, 0);
        acc[1][1] = __builtin_amdgcn_mfma_f32_16x16x32_bf16(a1, b1, acc[1][1], 0, 0, 0);
    }
    #pragma unroll
    for (int i = 0; i < 2; ++i)
        #pragma unroll
        for (int jn = 0; jn < 2; ++jn)
            #pragma unroll
            for (int t = 0; t < 4; ++t) {
                int grow = row0 + wm + i * 16 + quad * 4 + t;
                int gcol = col0 + wn + jn * 16 + r;
                if (grow >= M) continue;
                float v = acc[i][jn][t];
                size_t off = (size_t)grow * N + gcol;
                if (EPI == 0) {
                    ((u16*)Cout)[off] = f2bf(v);
                } else if (EPI == 2) {
                    Rf[off] += v + ldf(bias, gcol, isf32);
                } else {
                    ((float*)Cout)[off] = v + ldf(bias, gcol, isf32) + Rf[off];
                }
            }
}

// ============ FALLBACK: round-4 geglu ============
__global__ __launch_bounds__(256) void k_gemm_geglu(const u16* __restrict__ A, const void* __restrict__ B,
                                                    const void* __restrict__ bias, u16* __restrict__ Out,
                                                    int M, int Nout, int K, int ldb,
                                                    const int* __restrict__ flagp) {
    int isf32 = *flagp;
    __shared__ u16 As[64][40];
    __shared__ u16 Bs[64][40];
    int tid = threadIdx.x;
    int row0 = blockIdx.x * 64, col0 = blockIdx.y * 64;
    int wave = tid >> 6, lane = tid & 63;
    int wm = (wave >> 1) * 32, wn = (wave & 1) * 32;
    int quad = lane >> 4, r = lane & 15;
    int arow = tid >> 2, akk = (tid & 3) * 8;
    int bnl = tid & 63, bkk = (tid >> 6) * 8;
    int garow = row0 + arow;
    f32x4 acc[2][2][2] = {};
    for (int p = 0; p < 2; ++p) {
        for (int k0 = 0; k0 < K; k0 += 32) {
            uint4 aval = {0u, 0u, 0u, 0u};
            if (garow < M) aval = *(const uint4*)(A + (size_t)garow * K + k0 + akk);
            u16 btmp[8];
            #pragma unroll
            for (int j = 0; j < 8; ++j)
                btmp[j] = ldbf(B, (size_t)(k0 + bkk + j) * ldb + p * Nout + col0 + bnl, isf32);
            __syncthreads();
            *(uint4*)(&As[arow][akk]) = aval;
            *(uint4*)(&Bs[bnl][bkk]) = *(uint4*)btmp;
            __syncthreads();
            bf16x8 a0 = *(const bf16x8*)(&As[wm + r][quad * 8]);
            bf16x8 a1 = *(const bf16x8*)(&As[wm + 16 + r][quad * 8]);
            bf16x8 b0 = *(const bf16x8*)(&Bs[wn + r][quad * 8]);
            bf16x8 b1 = *(const bf16x8*)(&Bs[wn + 16 + r][quad * 8]);
            acc[p][0][0] = __builtin_amdgcn_mfma_f32_16x16x32_bf16(a0, b0, acc[p][0][0], 0, 0, 0);
            acc[p][0][1] = __builtin_amdgcn_mfma_f32_16x16x32_bf16(a0, b1, acc[p][0][1], 0, 0, 0);
            acc[p][1][0] = __builtin_amdgcn_mfma_f32_16x16x32_bf16(a1, b0, acc[p][1][0], 0, 0, 0);
            acc[p][1][1] = __builtin_amdgcn_mfma_f32_16x16x32_bf16(a1, b1, acc[p][1][1], 0, 0, 0);
        }
    }
    #pragma unroll
    for (int i = 0; i < 2; ++i)
        #pragma unroll
        for (int jn = 0; jn < 2; ++jn)
            #pragma unroll
            for (int t = 0; t < 4; ++t) {
                int grow = row0 + wm + i * 16 + quad * 4 + t;
                int gcol = col0 + wn + jn * 16 + r;
                if (grow >= M) continue;
                float a = acc[0][i][jn][t] + ldf(bias, gcol, isf32);
                float u = acc[1][i][jn][t] + ldf(bias, Nout + gcol, isf32);
                float th = tanhf(0.7978845608f * (u + 0.044715f * u * u * u));
                float gl = 0.5f * u * (1.f + th);
                Out[(size_t)grow * Nout + gcol] = f2bf(a * gl);
            }
}

// ---------------- MFMA flash attention, KVBLK=64, K+V LDS-staged, exp2-domain softmax ----------------
// Per wave: 16 q rows. Per tile: 64 kv. K staged straight [kv][d]; V transposed [d][kv].
// Softmax in log2 domain (scores scaled by 0.125*log2e); per-tile cross-lane reductions,
// alpha-exp, rescale, and barriers are HALF of the KVBLK=32 version.
__global__ __launch_bounds__(256) void k_attn_flash(const u16* __restrict__ Q, const u16* __restrict__ K,
                                                    const u16* __restrict__ V, u16* __restrict__ O,
                                                    int N, int Mkv, int H, int ldq, int ldkv, int ldo) {
    __shared__ u16 KT[64][72];       // K rows as-is: [kv][d]
    __shared__ u16 VT[64][72];       // V transposed: [d][kv]
    __shared__ u16 Sp[4][16][72];    // P per wave: [q][kv0..63]
    const float SC = 0.18033688f;    // 0.125 * log2(e)
    int nt = N / 64;
    int qt = blockIdx.x % nt;
    int bh = blockIdx.x / nt;
    int h = bh % H, b = bh / H;
    int tid = threadIdx.x, wave = tid >> 6, lane = tid & 63;
    int quad = lane >> 4, r = lane & 15;
    int q0 = qt * 64 + wave * 16;

    const u16* qbase = Q + ((size_t)(b * N + q0 + r)) * ldq + h * 64;
    bf16x8 aq0 = *(const bf16x8*)(qbase + quad * 8);
    bf16x8 aq1 = *(const bf16x8*)(qbase + 32 + quad * 8);

    f32x4 accO[4] = {};
    float m_i[4] = {-1e30f, -1e30f, -1e30f, -1e30f};
    float l_i[4] = {0.f, 0.f, 0.f, 0.f};

    // staging: 256 threads cover 64 rows x 64 cols; thread -> row tid>>2, col halves
    int srow = tid >> 2;
    int scol = (tid & 3) * 8;        // first uint4 at scol, second at scol+32 (coalesced)

    for (int kv0 = 0; kv0 < Mkv; kv0 += 64) {
        int krow = min(kv0 + srow, Mkv - 1);
        const u16* kp = K + ((size_t)(b * Mkv + krow)) * ldkv + h * 64;
        const u16* vp = V + ((size_t)(b * Mkv + krow)) * ldkv + h * 64;
        uint4 ka = *(const uint4*)(kp + scol);
        uint4 kb = *(const uint4*)(kp + scol + 32);
        uint4 va = *(const uint4*)(vp + scol);
        uint4 vb = *(const uint4*)(vp + scol + 32);

        __syncthreads();             // prior tile's LDS reads complete
        *(uint4*)(&KT[srow][scol]) = ka;
        *(uint4*)(&KT[srow][scol + 32]) = kb;
        u16 tmp[16];
        *(uint4*)tmp = va; *(uint4*)(tmp + 8) = vb;
        #pragma unroll
        for (int j = 0; j < 8; ++j) {
            VT[scol + j][srow] = tmp[j];
            VT[scol + 32 + j][srow] = tmp[8 + j];
        }
        __syncthreads();

        // K frags from LDS: kv rows g*16+r, d halves
        bf16x8 bk[4][2];
        #pragma unroll
        for (int g = 0; g < 4; ++g) {
            bk[g][0] = *(const bf16x8*)(&KT[g * 16 + r][quad * 8]);
            bk[g][1] = *(const bf16x8*)(&KT[g * 16 + r][32 + quad * 8]);
        }
        f32x4 s[4] = {};
        #pragma unroll
        for (int g = 0; g < 4; ++g) {
            s[g] = __builtin_amdgcn_mfma_f32_16x16x32_bf16(aq0, bk[g][0], s[g], 0, 0, 0);
            s[g] = __builtin_amdgcn_mfma_f32_16x16x32_bf16(aq1, bk[g][1], s[g], 0, 0, 0);
        }
        bool msk[4];
        #pragma unroll
        for (int g = 0; g < 4; ++g) msk[g] = (kv0 + g * 16 + r) >= Mkv;

        #pragma unroll
        for (int t = 0; t < 4; ++t) {
            float v0 = msk[0] ? -1e30f : s[0][t] * SC;
            float v1 = msk[1] ? -1e30f : s[1][t] * SC;
            float v2 = msk[2] ? -1e30f : s[2][t] * SC;
            float v3 = msk[3] ? -1e30f : s[3][t] * SC;
            float mx = fmaxf(fmaxf(v0, v1), fmaxf(v2, v3));
            mx = fmaxf(mx, __shfl_xor(mx, 1));
            mx = fmaxf(mx, __shfl_xor(mx, 2));
            mx = fmaxf(mx, __shfl_xor(mx, 4));
            mx = fmaxf(mx, __shfl_xor(mx, 8));
            float mn = fmaxf(m_i[t], mx);
            float alpha = exp2f(m_i[t] - mn);
            float p0 = exp2f(v0 - mn);
            float p1 = exp2f(v1 - mn);
            float p2 = exp2f(v2 - mn);
            float p3 = exp2f(v3 - mn);
            float ps = (p0 + p1) + (p2 + p3);
            ps += __shfl_xor(ps, 1);
            ps += __shfl_xor(ps, 2);
            ps += __shfl_xor(ps, 4);
            ps += __shfl_xor(ps, 8);
            l_i[t] = l_i[t] * alpha + ps;
            m_i[t] = mn;
            accO[0][t] *= alpha; accO[1][t] *= alpha; accO[2][t] *= alpha; accO[3][t] *= alpha;
            int qr = quad * 4 + t;
            Sp[wave][qr][r] = f2bf(p0);
            Sp[wave][qr][16 + r] = f2bf(p1);
            Sp[wave][qr][32 + r] = f2bf(p2);
            Sp[wave][qr][48 + r] = f2bf(p3);
        }

        // PV: P rows (q) x V^T; kv halves 0..31 / 32..63 (per-wave Sp, in-wave lgkm ordering)
        bf16x8 ap0 = *(const bf16x8*)(&Sp[wave][r][quad * 8]);
        bf16x8 ap1 = *(const bf16x8*)(&Sp[wave][r][32 + quad * 8]);
        #pragma unroll
        for (int g = 0; g < 4; ++g) {
            bf16x8 bv0 = *(const bf16x8*)(&VT[g * 16 + r][quad * 8]);
            bf16x8 bv1 = *(const bf16x8*)(&VT[g * 16 + r][32 + quad * 8]);
            accO[g] = __builtin_amdgcn_mfma_f32_16x16x32_bf16(ap0, bv0, accO[g], 0, 0, 0);
            accO[g] = __builtin_amdgcn_mfma_f32_16x16x32_bf16(ap1, bv1, accO[g], 0, 0, 0);
        }
    }

    u16* ob = O + ((size_t)(b * N + q0)) * ldo + h * 64;
    #pragma unroll
    for (int t = 0; t < 4; ++t) {
        float inv = 1.f / l_i[t];
        #pragma unroll
        for (int g = 0; g < 4; ++g)
            ob[(size_t)(quad * 4 + t) * ldo + g * 16 + r] = f2bf(accO[g][t] * inv);
    }
}

extern "C" void kernel_launch(void* const* d_in, const int* in_sizes, int n_in,
                              void* d_out, int out_size, void* d_ws, size_t ws_size,
                              hipStream_t stream) {
    const void* x    = d_in[0];
    const void* ctx  = d_in[1];
    const void* g1   = d_in[2];
    const void* be1  = d_in[3];
    const void* wq1  = d_in[4];
    const void* wk1  = d_in[5];
    const void* wv1  = d_in[6];
    const void* wo1  = d_in[7];
    const void* bo1  = d_in[8];
    const void* g2   = d_in[9];
    const void* be2  = d_in[10];
    const void* wq2  = d_in[11];
    const void* wk2  = d_in[12];
    const void* wv2  = d_in[13];
    const void* wo2  = d_in[14];
    const void* bo2  = d_in[15];
    const void* g3   = d_in[16];
    const void* be3  = d_in[17];
    const void* wff1 = d_in[18];
    const void* bff1 = d_in[19];
    const void* wff2 = d_in[20];
    const void* bff2 = d_in[21];

    const int BT = 4096, D = 1280;
    dim3 blk(256);
    char* ws = (char*)d_ws;

    const size_t NEED_FAST = 117393664;
    if (ws_size >= NEED_FAST) {
        // ---------- fast path ----------
        int*   flag   = (int*)(ws);
        u16* lnout    = (u16*)(ws + 256);            // 4096x1280 bf16
        u16* qkv      = (u16*)(ws + 10486016);       // 4096x3840 bf16 (region R)
        u16* attnout  = (u16*)(ws + 10486016 + 31457280);
        u16* gbuf     = (u16*)(ws + 10486016);       // 4096x5120 bf16, aliases qkv+attnout
        u16* ctxb     = (u16*)(ws + 52429056);       // 308x768 bf16
        u16* kv2      = (u16*)(ws + 52902144);       // 308x2560 bf16
        u16* wqkv1t   = (u16*)(ws + 54479104);       // [3840][1280]
        u16* wo1t     = (u16*)(ws + 64309504);       // [1280][1280]
        u16* wq2t     = (u16*)(ws + 67586304);
        u16* wkv2t    = (u16*)(ws + 70863104);       // [2560][768]
        u16* wo2t     = (u16*)(ws + 74795264);
        u16* wff1t    = (u16*)(ws + 78072064);       // [10240][1280]
        u16* wff2t    = (u16*)(ws + 104286464);      // [1280][5120]
        float* pff2   = (float*)(ws + 54479104);     // FF2 split-K partial (21 MB); weights dead there
        float* pWO    = (float*)(ws + 10486016);     // WO1/WO2 split-K partial (21 MB) in dead qkv region
        float* xres   = (float*)d_out;               // residual lives in the fp32 output

        k_detect<<<dim3(1), blk, 0, stream>>>((const u16*)x, flag);
        k_b2f<<<dim3((BT * D + 255) / 256), blk, 0, stream>>>(x, xres, BT * D, flag);
        // weight transposes (batched: 10 -> 5 launches)
        k_transpose3<<<dim3(40, 40, 3), blk, 0, stream>>>(wq1, wk1, wv1,
                                                          wqkv1t, wqkv1t + 1280 * 1280,
                                                          wqkv1t + 2 * 1280 * 1280, 1280, 1280, flag);
        k_transpose3<<<dim3(40, 40, 3), blk, 0, stream>>>(wo1, wq2, wo2,
                                                          wo1t, wq2t, wo2t, 1280, 1280, flag);
        k_transpose3<<<dim3(24, 40, 2), blk, 0, stream>>>(wk2, wv2, wv2,
                                                          wkv2t, wkv2t + 1280 * 768,
                                                          wkv2t + 1280 * 768, 768, 1280, flag);
        k_transpose<<<dim3(40, 320), blk, 0, stream>>>(wff1, wff1t, 1280, 10240, flag);
        k_transpose<<<dim3(160, 40), blk, 0, stream>>>(wff2, wff2t, 5120, 1280, flag);
        k_cvt<<<dim3((308 * 768 + 255) / 256), blk, 0, stream>>>(ctx, ctxb, 308 * 768, flag);
        // --- self attention ---
        k_layernorm<<<dim3(BT), blk, 0, stream>>>(xres, nullptr, g1, be1, lnout, D, flag);
        k_gemm8<0><<<dim3(16, 15), dim3(512), 0, stream>>>(lnout, wqkv1t, qkv, nullptr, BT, 3840, D, flag);
        k_attn_flash<<<dim3(16 * 80), blk, 0, stream>>>(qkv, qkv + 1280, qkv + 2560, attnout,
                                                        1024, 1024, 20, 3840, 3840, 1280);
        // WO1: split-K=2; kz1 partial -> pWO (qkv region now dead); folded by LN2
        k_gemm_t<2><<<dim3(32, 10, 2), blk, 0, stream>>>(attnout, wo1t, pWO, xres, bo1, BT, D, D, flag);
        // --- cross attention ---
        k_layernorm<<<dim3(BT), blk, 0, stream>>>(xres, pWO, g2, be2, lnout, D, flag);
        k_gemm_t<0><<<dim3(32, 10), blk, 0, stream>>>(lnout, wq2t, qkv, nullptr, nullptr, BT, D, D, flag);
        k_gemm_t<0><<<dim3(3, 20), blk, 0, stream>>>(ctxb, wkv2t, kv2, nullptr, nullptr, 308, 2560, 768, flag);
        k_attn_flash<<<dim3(16 * 80), blk, 0, stream>>>(qkv, kv2, kv2 + 1280, attnout,
                                                        1024, 77, 20, 1280, 2560, 1280);
        // WO2: split-K=2; kz1 partial -> pWO (qkv dead again); folded by LN3
        k_gemm_t<2><<<dim3(32, 10, 2), blk, 0, stream>>>(attnout, wo2t, pWO, xres, bo2, BT, D, D, flag);
        // --- GEGLU FF ---
        k_layernorm<<<dim3(BT), blk, 0, stream>>>(xres, pWO, g3, be3, lnout, D, flag);
        k_gemm8<1><<<dim3(16, 40), dim3(512), 0, stream>>>(lnout, wff1t, gbuf, bff1, BT, 10240, D, flag);
        // FF2: split-K=2; kz1 partial -> pff2; fold with k_addp (final output, no following LN)
        k_gemm_t<2><<<dim3(32, 10, 2), blk, 0, stream>>>(gbuf, wff2t, pff2, xres, bff2, BT, D, 5120, flag);
        k_addp<<<dim3(2048), blk, 0, stream>>>(xres, pff2, BT * D / 4);
    } else {
        // ---------- fallback: round-4 path (known-good, ~75 MB ws) ----------
        int*   flag    = (int*)(ws);
        float* xres    = (float*)(ws + 256);
        u16* lnout     = (u16*)(ws + 20971776);
        u16* q         = (u16*)(ws + 31457536);
        u16* kbuf      = (u16*)(ws + 41943296);
        u16* vbuf      = (u16*)(ws + 52429056);
        u16* attnout   = (u16*)(ws + 62914816);
        u16* k2        = (u16*)(ws + 73400576);
        u16* v2        = (u16*)(ws + 74189056);
        u16* gbuf      = (u16*)(ws + 31457536);

        dim3 g_gemm(64, 20);
        dim3 g_kv(5, 20);
        dim3 g_attn(16 * 80);

        k_detect<<<dim3(1), blk, 0, stream>>>((const u16*)x, flag);
        k_b2f<<<dim3((BT * D + 255) / 256), blk, 0, stream>>>(x, xres, BT * D, flag);
        k_layernorm<<<dim3(BT), blk, 0, stream>>>(xres, nullptr, g1, be1, lnout, D, flag);
        k_gemm<0, false><<<g_gemm, blk, 0, stream>>>(lnout, wq1, q, nullptr, nullptr, BT, D, D, flag);
        k_gemm<0, false><<<g_gemm, blk, 0, stream>>>(lnout, wk1, kbuf, nullptr, nullptr, BT, D, D, flag);
        k_gemm<0, false><<<g_gemm, blk, 0, stream>>>(lnout, wv1, vbuf, nullptr, nullptr, BT, D, D, flag);
        k_attn_flash<<<g_attn, blk, 0, stream>>>(q, kbuf, vbuf, attnout, 1024, 1024, 20, 1280, 1280, 1280);
        k_gemm<2, false><<<g_gemm, blk, 0, stream>>>(attnout, wo1, nullptr, xres, bo1, BT, D, D, flag);
        k_layernorm<<<dim3(BT), blk, 0, stream>>>(xres, nullptr, g2, be2, lnout, D, flag);
        k_gemm<0, false><<<g_gemm, blk, 0, stream>>>(lnout, wq2, q, nullptr, nullptr, BT, D, D, flag);
        k_gemm<0, true><<<g_kv, blk, 0, stream>>>(ctx, wk2, k2, nullptr, nullptr, 308, D, 768, flag);
        k_gemm<0, true><<<g_kv, blk, 0, stream>>>(ctx, wv2, v2, nullptr, nullptr, 308, D, 768, flag);
        k_attn_flash<<<g_attn, blk, 0, stream>>>(q, k2, v2, attnout, 1024, 77, 20, 1280, 1280, 1280);
        k_gemm<2, false><<<g_gemm, blk, 0, stream>>>(attnout, wo2, nullptr, xres, bo2, BT, D, D, flag);
        k_layernorm<<<dim3(BT), blk, 0, stream>>>(xres, nullptr, g3, be3, lnout, D, flag);
        k_gemm_geglu<<<dim3(64, 80), blk, 0, stream>>>(lnout, wff1, bff1, gbuf, BT, 5120, D, 10240, flag);
        k_gemm<3, false><<<g_gemm, blk, 0, stream>>>(gbuf, wff2, d_out, xres, bff2, BT, D, 5120, flag);
    }
}

// Round 10
// 776.656 us; speedup vs baseline: 1.0835x; 1.0701x over previous
//
#include <hip/hip_runtime.h>

typedef unsigned short u16;
typedef __bf16 bf16x8 __attribute__((ext_vector_type(8)));
typedef float f32x4 __attribute__((ext_vector_type(4)));

static __device__ __forceinline__ float bf2f(u16 u) {
    union { unsigned int i; float f; } v; v.i = ((unsigned int)u) << 16; return v.f;
}
static __device__ __forceinline__ u16 f2bf(float f) {
    union { float f; unsigned int i; } v; v.f = f;
    unsigned int b = v.i;
    b += 0x7fffu + ((b >> 16) & 1u);   // RNE
    return (u16)(b >> 16);
}
static __device__ __forceinline__ u16 ldbf(const void* p, size_t i, int isf32) {
    return isf32 ? f2bf(((const float*)p)[i]) : ((const u16*)p)[i];
}
static __device__ __forceinline__ float ldf(const void* p, size_t i, int isf32) {
    return isf32 ? ((const float*)p)[i] : bf2f(((const u16*)p)[i]);
}
// async global->LDS, 16B per lane; lds dest = wave-uniform base + lane*16 (m97/m104)
static __device__ __forceinline__ void glds16(const u16* g, u16* l) {
    __builtin_amdgcn_global_load_lds(
        (const __attribute__((address_space(1))) unsigned int*)g,
        (__attribute__((address_space(3))) unsigned int*)l,
        16, 0, 0);
}
// XCD-chunked bijective remap (T1, m192). Used ONLY for k_gemm8.
static __device__ __forceinline__ int xcd_swz(int lid, int nwg) {
    return ((nwg & 7) == 0) ? ((lid & 7) * (nwg >> 3) + (lid >> 3)) : lid;
}

// ---------------- dtype detector (insurance; inputs measured fp32) ----------------
__global__ __launch_bounds__(256) void k_detect(const u16* __restrict__ xu, int* __restrict__ flag) {
    u16 v = xu[threadIdx.x * 2];
    int e = (v >> 7) & 0xFF;
    int sane = (e >= 87 && e <= 133) ? 1 : 0;
    int total = __syncthreads_count(sane);
    if (threadIdx.x == 0) flag[0] = (total < 192) ? 1 : 0;
}

// ---------------- x -> f32 residual stream ----------------
__global__ __launch_bounds__(256) void k_b2f(const void* __restrict__ in, float* __restrict__ out, int n,
                                             const int* __restrict__ flagp) {
    int isf32 = *flagp;
    int i = blockIdx.x * 256 + threadIdx.x;
    if (i < n) out[i] = ldf(in, i, isf32);
}

// ---------------- external -> bf16 convert ----------------
__global__ __launch_bounds__(256) void k_cvt(const void* __restrict__ in, u16* __restrict__ out, int n,
                                             const int* __restrict__ flagp) {
    int isf32 = *flagp;
    int i = blockIdx.x * 256 + threadIdx.x;
    if (i < n) out[i] = ldbf(in, i, isf32);
}

// ---------------- split-K reduce: X += P (fp32, vectorized) ----------------
__global__ __launch_bounds__(256) void k_addp(float* __restrict__ X, const float* __restrict__ P, int n4) {
    int i = blockIdx.x * 256 + threadIdx.x;
    int stride = gridDim.x * 256;
    for (; i < n4; i += stride) {
        f32x4 a = ((const f32x4*)X)[i];
        f32x4 b = ((const f32x4*)P)[i];
        a[0] += b[0]; a[1] += b[1]; a[2] += b[2]; a[3] += b[3];
        ((f32x4*)X)[i] = a;
    }
}

// ---------------- weight transpose+convert: W[K,N] (ext) -> Wt[N,K] bf16 ----------------
__global__ __launch_bounds__(256) void k_transpose(const void* __restrict__ W, u16* __restrict__ Wt,
                                                   int K, int N, const int* __restrict__ flagp) {
    int isf32 = *flagp;
    __shared__ u16 T[32][33];
    int k0 = blockIdx.x * 32, n0 = blockIdx.y * 32;
    int tid = threadIdx.x;
    int c = tid & 31, rr = tid >> 5;
    #pragma unroll
    for (int j = 0; j < 4; ++j) {
        int k = rr + j * 8;
        T[k][c] = ldbf(W, (size_t)(k0 + k) * N + n0 + c, isf32);
    }
    __syncthreads();
    #pragma unroll
    for (int j = 0; j < 4; ++j) {
        int n = rr + j * 8;
        Wt[(size_t)(n0 + n) * K + k0 + c] = T[c][n];
    }
}

// ---------------- batched transpose: up to 3 same-shape weights in one launch ----------------
__global__ __launch_bounds__(256) void k_transpose3(const void* __restrict__ W0, const void* __restrict__ W1,
                                                    const void* __restrict__ W2,
                                                    u16* __restrict__ D0, u16* __restrict__ D1,
                                                    u16* __restrict__ D2,
                                                    int K, int N, const int* __restrict__ flagp) {
    int isf32 = *flagp;
    int z = blockIdx.z;
    const void* W = (z == 0) ? W0 : (z == 1) ? W1 : W2;
    u16* Wt = (z == 0) ? D0 : (z == 1) ? D1 : D2;
    __shared__ u16 T[32][33];
    int k0 = blockIdx.x * 32, n0 = blockIdx.y * 32;
    int tid = threadIdx.x;
    int c = tid & 31, rr = tid >> 5;
    #pragma unroll
    for (int j = 0; j < 4; ++j) {
        int k = rr + j * 8;
        T[k][c] = ldbf(W, (size_t)(k0 + k) * N + n0 + c, isf32);
    }
    __syncthreads();
    #pragma unroll
    for (int j = 0; j < 4; ++j) {
        int n = rr + j * 8;
        Wt[(size_t)(n0 + n) * K + k0 + c] = T[c][n];
    }
}

// ---------------- LayerNorm: fp32 in -> bf16 out; optional split-K partial fold ----------------
// If P != null: x[i] += P[i] first (residual write-back), then normalize the summed value.
__global__ __launch_bounds__(256) void k_layernorm(float* __restrict__ X, const float* __restrict__ P,
                                                   const void* __restrict__ G, const void* __restrict__ Bb,
                                                   u16* __restrict__ Y, int D,
                                                   const int* __restrict__ flagp) {
    int isf32 = *flagp;
    int row = blockIdx.x;
    float* xr = X + (size_t)row * D;
    const float* pr = P ? (P + (size_t)row * D) : nullptr;
    float s = 0.f, s2 = 0.f;
    for (int i = threadIdx.x; i < D; i += 256) {
        float v = xr[i] + (P ? pr[i] : 0.f);
        s += v; s2 += v * v;
    }
    #pragma unroll
    for (int off = 32; off; off >>= 1) { s += __shfl_down(s, off); s2 += __shfl_down(s2, off); }
    __shared__ float rs[4], rs2[4];
    __shared__ float stat[2];
    int w = threadIdx.x >> 6;
    if ((threadIdx.x & 63) == 0) { rs[w] = s; rs2[w] = s2; }
    __syncthreads();
    if (threadIdx.x == 0) {
        float ts = rs[0] + rs[1] + rs[2] + rs[3];
        float ts2 = rs2[0] + rs2[1] + rs2[2] + rs2[3];
        float mu = ts / D;
        float var = ts2 / D - mu * mu;
        stat[0] = mu; stat[1] = rsqrtf(var + 1e-5f);
    }
    __syncthreads();
    float mu = stat[0], rstd = stat[1];
    u16* yr = Y + (size_t)row * D;
    for (int i = threadIdx.x; i < D; i += 256) {
        float v = xr[i] + (P ? pr[i] : 0.f);
        if (P) xr[i] = v;                      // residual stream now holds the full sum
        yr[i] = f2bf((v - mu) * rstd * ldf(G, i, isf32) + ldf(Bb, i, isf32));
    }
}

// ============ 256x256 GEMM, overlapped 4-phase schedule (T1..T5 + counted-lgkm) ============
// (parked; three schedule variants measured identical)
template <int EPI>
__global__ __launch_bounds__(512, 2) void k_gemm8(const u16* __restrict__ A, const u16* __restrict__ Bt,
                                                  void* __restrict__ Cout, const void* __restrict__ bias,
                                                  int M, int N, int K, const int* __restrict__ flagp) {
    __shared__ __align__(16) u16 sm[65536];   // 128 KiB static
    const int tid = threadIdx.x;
    const int w = tid >> 6;
    const int lane = tid & 63;
    const int quad = lane >> 4, r = lane & 15;
    const int wm = w >> 2, wn = w & 3;          // 2 x 4 wave grid
    const int lid = blockIdx.x + blockIdx.y * gridDim.x;
    const int nid = xcd_swz(lid, gridDim.x * gridDim.y);
    const int row0 = (nid % gridDim.x) * 256;
    const int col0 = (nid / gridDim.x) * 256;
    const int NT = K >> 6;

    const u16* aP[2][2];
    const u16* bP[2][2];
    #pragma unroll
    for (int j = 0; j < 2; ++j) {
        int c = tid + w * 64 + j * 64;          // = w*128 + j*64 + lane
        int rj = c >> 3;                        // row within half (0..127)
        int qe = (c & 7) ^ (rj & 7);            // inverse-swizzled global chunk
        #pragma unroll
        for (int h = 0; h < 2; ++h) {
            int gr = h * 128 + rj;
            aP[h][j] = A + (size_t)(row0 + gr) * K + qe * 8;
            int n = col0 + gr;
            int m = (EPI == 1) ? (((n >> 4) & 1) * 5120 + (n >> 5) * 16 + (n & 15)) : n;
            bP[h][j] = Bt + (size_t)m * K + qe * 8;
        }
    }
    auto stageA = [&](int h, int t) {
        u16* base = sm + (t & 1) * 32768 + h * 8192 + w * 1024;
        glds16(aP[h][0] + t * 64, base);
        glds16(aP[h][1] + t * 64, base + 512);
    };
    auto stageB = [&](int h, int t) {
        u16* base = sm + (t & 1) * 32768 + 16384 + h * 8192 + w * 1024;
        glds16(bP[h][0] + t * 64, base);
        glds16(bP[h][1] + t * 64, base + 512);
    };

    f32x4 acc[2][2][4][2] = {};
    const int xq = r & 7;
    bf16x8 afA[4][2], afB[4][2], bf0[2][2], bf1[2][2];

    auto readA = [&](bf16x8 (&dst)[4][2], int Ab, int half) {
        #pragma unroll
        for (int i = 0; i < 4; ++i) {
            int ar = half * 128 + wm * 64 + i * 16 + r;
            #pragma unroll
            for (int ks = 0; ks < 2; ++ks)
                dst[i][ks] = *(const bf16x8*)(sm + Ab + ar * 64 + (((ks * 4 + quad) ^ xq) * 8));
        }
    };
    auto readB = [&](bf16x8 (&dst)[2][2], int Bb, int half) {
        #pragma unroll
        for (int g = 0; g < 2; ++g) {
            int br = half * 128 + wn * 32 + g * 16 + r;
            #pragma unroll
            for (int ks = 0; ks < 2; ++ks)
                dst[g][ks] = *(const bf16x8*)(sm + Bb + br * 64 + (((ks * 4 + quad) ^ xq) * 8));
        }
    };
    auto domfma = [&](int qm, int qn, bf16x8 (&a)[4][2], bf16x8 (&b)[2][2]) {
        #pragma unroll
        for (int ks = 0; ks < 2; ++ks)
            #pragma unroll
            for (int i = 0; i < 4; ++i)
                #pragma unroll
                for (int g = 0; g < 2; ++g)
                    acc[qm][qn][i][g] = __builtin_amdgcn_mfma_f32_16x16x32_bf16(
                        a[i][ks], b[g][ks], acc[qm][qn][i][g], 0, 0, 0);
    };

    // prologue: tile 0 complete + halves0 of tile 1; vmcnt(4) -> tile 0 landed
    stageA(0, 0); stageB(0, 0); stageA(1, 0); stageB(1, 0);
    if (NT > 1) {
        stageA(0, 1); stageB(0, 1);
        asm volatile("s_waitcnt vmcnt(4)" ::: "memory");
    } else {
        asm volatile("s_waitcnt vmcnt(0)" ::: "memory");
    }
    __builtin_amdgcn_s_barrier();
    readA(afA, 0, 0);
    readB(bf0, 16384, 0);

    for (int t = 0; t < NT; ++t) {
        const int Ab = (t & 1) * 32768;
        const int Bb = Ab + 16384;
        const int Abn = ((t + 1) & 1) * 32768;
        // ---- ph0: MFMA(afA,bf0); prefetch bf1 under it ----
        readB(bf1, Bb, 1);
        __builtin_amdgcn_sched_barrier(0);
        __builtin_amdgcn_s_setprio(1);
        domfma(0, 0, afA, bf0);
        __builtin_amdgcn_s_setprio(0);
        if (t + 1 < NT) stageA(1, t + 1);
        __builtin_amdgcn_s_barrier();
        // ---- ph1: MFMA(afA,bf1); prefetch afB under it ----
        readA(afB, Ab, 1);
        __builtin_amdgcn_sched_barrier(0);
        __builtin_amdgcn_s_setprio(1);
        domfma(0, 1, afA, bf1);
        __builtin_amdgcn_s_setprio(0);
        if (t + 1 < NT) stageB(1, t + 1);
        __builtin_amdgcn_s_barrier();
        // ---- ph2: MFMA(afB,bf1) ----
        __builtin_amdgcn_s_setprio(1);
        domfma(1, 1, afB, bf1);
        __builtin_amdgcn_s_setprio(0);
        if (t + 2 < NT) stageA(0, t + 2);
        __builtin_amdgcn_s_barrier();
        // ---- ph3: MFMA(afB,bf0); vmcnt-gate + next-tile frag issue ----
        __builtin_amdgcn_s_setprio(1);
        domfma(1, 0, afB, bf0);
        __builtin_amdgcn_s_setprio(0);
        if (t + 2 < NT) stageB(0, t + 2);
        if (t + 2 < NT) asm volatile("s_waitcnt vmcnt(4)" ::: "memory");
        else            asm volatile("s_waitcnt vmcnt(0)" ::: "memory");
        __builtin_amdgcn_s_barrier();
        if (t + 1 < NT) {
            readA(afA, Abn, 0);
            readB(bf0, Abn + 16384, 0);
        }
    }

    if (EPI == 0) {
        u16* C = (u16*)Cout;
        #pragma unroll
        for (int qm = 0; qm < 2; ++qm) {
            #pragma unroll
            for (int qn = 0; qn < 2; ++qn) {
                #pragma unroll
                for (int i = 0; i < 4; ++i) {
                    int grow = row0 + qm * 128 + wm * 64 + i * 16 + quad * 4;
                    #pragma unroll
                    for (int g = 0; g < 2; ++g) {
                        int gcol = col0 + qn * 128 + wn * 32 + g * 16 + r;
                        #pragma unroll
                        for (int t4 = 0; t4 < 4; ++t4)
                            C[(size_t)(grow + t4) * N + gcol] = f2bf(acc[qm][qn][i][g][t4]);
                    }
                }
            }
        }
    } else {
        const int isf32 = *flagp;
        u16* C = (u16*)Cout;  // [M][5120]
        #pragma unroll
        for (int qm = 0; qm < 2; ++qm) {
            #pragma unroll
            for (int qn = 0; qn < 2; ++qn) {
                int ncb = col0 + qn * 128 + wn * 32;
                int oc = (ncb >> 1) + r;
                float bva = ldf(bias, oc, isf32);
                float bvu = ldf(bias, 5120 + oc, isf32);
                #pragma unroll
                for (int i = 0; i < 4; ++i) {
                    int grow = row0 + qm * 128 + wm * 64 + i * 16 + quad * 4;
                    #pragma unroll
                    for (int t4 = 0; t4 < 4; ++t4) {
                        float a = acc[qm][qn][i][0][t4] + bva;
                        float u = acc[qm][qn][i][1][t4] + bvu;
                        float z2 = 1.5957691216f * (u + 0.044715f * u * u * u);
                        float gl = u * __builtin_amdgcn_rcpf(1.f + __expf(-z2));
                        C[(size_t)(grow + t4) * 5120 + oc] = f2bf(a * gl);
                    }
                }
            }
        }
    }
}

// ============ FAST PATH: 128x128 tile GEMM via global_load_lds, xor-swizzled LDS ============
// EPI: 0 = bf16 store; 2 = xres += acc + bias (fp32). Split-K (gridDim.z==2):
// kz=0 -> xres += acc + bias (non-atomic, sole owner); kz=1 -> fp32 partial into Cout;
// the partial is folded by k_addp or by the following k_layernorm(P=partial).
template <int EPI>
__global__ __launch_bounds__(256) void k_gemm_t(const u16* __restrict__ A, const u16* __restrict__ Bt,
                                                void* __restrict__ Cout, float* __restrict__ Rf,
                                                const void* __restrict__ bias,
                                                int M, int N, int K, const int* __restrict__ flagp) {
    int isf32 = *flagp;
    __shared__ __align__(16) u16 As[4096];
    __shared__ __align__(16) u16 Bs[4096];
    int tid = threadIdx.x;
    int row0 = blockIdx.x * 128, col0 = blockIdx.y * 128;
    int S = gridDim.z, kz = blockIdx.z;
    int kseg = K / S;
    int kb = kz * kseg, ke = kb + kseg;
    int wave = tid >> 6, lane = tid & 63;
    int wm = (wave >> 1) * 64, wn = (wave & 1) * 64;
    int quad = lane >> 4, r = lane & 15;
    int c0 = wave * 64 + lane, c1 = 256 + c0;
    int ar0 = c0 >> 2, aq0 = (c0 & 3) ^ ((ar0 >> 1) & 3);
    int ar1 = c1 >> 2, aq1 = (c1 & 3) ^ ((ar1 >> 1) & 3);
    const u16* Ag0 = A + (size_t)min(row0 + ar0, M - 1) * K + aq0 * 8;
    const u16* Ag1 = A + (size_t)min(row0 + ar1, M - 1) * K + aq1 * 8;
    const u16* Bg0 = Bt + (size_t)(col0 + ar0) * K + aq0 * 8;
    const u16* Bg1 = Bt + (size_t)(col0 + ar1) * K + aq1 * 8;
    u16* lA0 = As + wave * 512;
    u16* lA1 = As + 2048 + wave * 512;
    u16* lB0 = Bs + wave * 512;
    u16* lB1 = Bs + 2048 + wave * 512;
    f32x4 acc[4][4] = {};
    for (int k0 = kb; k0 < ke; k0 += 32) {
        __syncthreads();
        glds16(Ag0 + k0, lA0);
        glds16(Ag1 + k0, lA1);
        glds16(Bg0 + k0, lB0);
        glds16(Bg1 + k0, lB1);
        __syncthreads();
        bf16x8 af[4], bfv[4];
        #pragma unroll
        for (int i = 0; i < 4; ++i) {
            int row = wm + i * 16 + r;
            af[i] = *(const bf16x8*)(As + (row * 4 + (quad ^ ((row >> 1) & 3))) * 8);
        }
        #pragma unroll
        for (int g = 0; g < 4; ++g) {
            int row = wn + g * 16 + r;
            bfv[g] = *(const bf16x8*)(Bs + (row * 4 + (quad ^ ((row >> 1) & 3))) * 8);
        }
        #pragma unroll
        for (int i = 0; i < 4; ++i)
            #pragma unroll
            for (int g = 0; g < 4; ++g)
                acc[i][g] = __builtin_amdgcn_mfma_f32_16x16x32_bf16(af[i], bfv[g], acc[i][g], 0, 0, 0);
    }
    #pragma unroll
    for (int i = 0; i < 4; ++i) {
        int grow = row0 + wm + i * 16 + quad * 4;
        if (grow >= M) continue;
        #pragma unroll
        for (int g = 0; g < 4; ++g) {
            int gcol = col0 + wn + g * 16 + r;
            float bv = (EPI == 2 && kz == 0) ? ldf(bias, gcol, isf32) : 0.f;
            #pragma unroll
            for (int t = 0; t < 4; ++t) {
                float v = acc[i][g][t];
                size_t off = (size_t)(grow + t) * N + gcol;
                if (EPI == 0) {
                    ((u16*)Cout)[off] = f2bf(v);
                } else {
                    if (kz == 0) Rf[off] += v + bv;          // sole owner of this element in z=0
                    else         ((float*)Cout)[off] = v;    // partial; folded later
                }
            }
        }
    }
}

// ============ FAST PATH: GEGLU ff1 via global_load_lds; Nout=5120 (fallback for gemm8) ====
__global__ __launch_bounds__(256) void k_geglu_t(const u16* __restrict__ A, const u16* __restrict__ Bt,
                                                 const void* __restrict__ bias, u16* __restrict__ Out,
                                                 int M, int K, const int* __restrict__ flagp) {
    const int Nout = 5120;
    int isf32 = *flagp;
    __shared__ __align__(16) u16 As[4096];
    __shared__ __align__(16) u16 Bs[4096];
    int tid = threadIdx.x;
    int row0 = blockIdx.x * 128, col0 = blockIdx.y * 64;
    int wave = tid >> 6, lane = tid & 63;
    int quad = lane >> 4, r = lane & 15;
    int c0 = wave * 64 + lane, c1 = 256 + c0;
    int ar0 = c0 >> 2, aq0 = (c0 & 3) ^ ((ar0 >> 1) & 3);
    int ar1 = c1 >> 2, aq1 = (c1 & 3) ^ ((ar1 >> 1) & 3);
    const u16* Ag0 = A + (size_t)min(row0 + ar0, M - 1) * K + aq0 * 8;
    const u16* Ag1 = A + (size_t)min(row0 + ar1, M - 1) * K + aq1 * 8;
    const u16* Bg0 = Bt + (size_t)((ar0 >> 6) * Nout + col0 + (ar0 & 63)) * K + aq0 * 8;
    const u16* Bg1 = Bt + (size_t)((ar1 >> 6) * Nout + col0 + (ar1 & 63)) * K + aq1 * 8;
    u16* lA0 = As + wave * 512;
    u16* lA1 = As + 2048 + wave * 512;
    u16* lB0 = Bs + wave * 512;
    u16* lB1 = Bs + 2048 + wave * 512;
    f32x4 acc[2][2][4] = {};
    for (int k0 = 0; k0 < K; k0 += 32) {
        __syncthreads();
        glds16(Ag0 + k0, lA0);
        glds16(Ag1 + k0, lA1);
        glds16(Bg0 + k0, lB0);
        glds16(Bg1 + k0, lB1);
        __syncthreads();
        bf16x8 af[2], bv[2][4];
        #pragma unroll
        for (int i = 0; i < 2; ++i) {
            int row = wave * 32 + i * 16 + r;
            af[i] = *(const bf16x8*)(As + (row * 4 + (quad ^ ((row >> 1) & 3))) * 8);
        }
        #pragma unroll
        for (int p = 0; p < 2; ++p)
            #pragma unroll
            for (int g = 0; g < 4; ++g) {
                int row = p * 64 + g * 16 + r;
                bv[p][g] = *(const bf16x8*)(Bs + (row * 4 + (quad ^ ((row >> 1) & 3))) * 8);
            }
        #pragma unroll
        for (int p = 0; p < 2; ++p)
            #pragma unroll
            for (int i = 0; i < 2; ++i)
                #pragma unroll
                for (int g = 0; g < 4; ++g)
                    acc[p][i][g] = __builtin_amdgcn_mfma_f32_16x16x32_bf16(af[i], bv[p][g], acc[p][i][g], 0, 0, 0);
    }
    #pragma unroll
    for (int i = 0; i < 2; ++i) {
        int grow = row0 + wave * 32 + i * 16 + quad * 4;
        #pragma unroll
        for (int g = 0; g < 4; ++g) {
            int gcol = col0 + g * 16 + r;
            float bva = ldf(bias, gcol, isf32);
            float bvu = ldf(bias, Nout + gcol, isf32);
            #pragma unroll
            for (int t = 0; t < 4; ++t) {
                float a = acc[0][i][g][t] + bva;
                float u = acc[1][i][g][t] + bvu;
                float z2 = 1.5957691216f * (u + 0.044715f * u * u * u);
                float gl = u * __builtin_amdgcn_rcpf(1.f + __expf(-z2));
                Out[(size_t)(grow + t) * Nout + gcol] = f2bf(a * gl);
            }
        }
    }
}

// ============ FALLBACK: round-4 64x64 GEMM (known-good) ============
template <int EPI, bool AEXT>
__global__ __launch_bounds__(256) void k_gemm(const void* __restrict__ A, const void* __restrict__ B,
                                              void* __restrict__ Cout, float* __restrict__ Rf,
                                              const void* __restrict__ bias,
                                              int M, int N, int K, const int* __restrict__ flagp) {
    int isf32 = *flagp;
    __shared__ u16 As[64][40];
    __shared__ u16 Bs[64][40];
    int tid = threadIdx.x;
    int row0 = blockIdx.x * 64, col0 = blockIdx.y * 64;
    int wave = tid >> 6, lane = tid & 63;
    int wm = (wave >> 1) * 32, wn = (wave & 1) * 32;
    int quad = lane >> 4, r = lane & 15;
    int arow = tid >> 2, akk = (tid & 3) * 8;
    int bnl = tid & 63, bkk = (tid >> 6) * 8;
    int garow = row0 + arow;
    f32x4 acc[2][2] = {};
    for (int k0 = 0; k0 < K; k0 += 32) {
        uint4 aval = {0u, 0u, 0u, 0u};
        if (garow < M) {
            if (AEXT && isf32) {
                const float* Af = (const float*)A;
                u16 t[8];
                #pragma unroll
                for (int j = 0; j < 8; ++j) t[j] = f2bf(Af[(size_t)garow * K + k0 + akk + j]);
                aval = *(uint4*)t;
            } else {
                aval = *(const uint4*)((const u16*)A + (size_t)garow * K + k0 + akk);
            }
        }
        u16 btmp[8];
        #pragma unroll
        for (int j = 0; j < 8; ++j) btmp[j] = ldbf(B, (size_t)(k0 + bkk + j) * N + col0 + bnl, isf32);
        __syncthreads();
        *(uint4*)(&As[arow][akk]) = aval;
        *(uint4*)(&Bs[bnl][bkk]) = *(uint4*)btmp;
        __syncthreads();
        bf16x8 a0 = *(const bf16x8*)(&As[wm + r][quad * 8]);
        bf16x8 a1 = *(const bf16x8*)(&As[wm + 16 + r][quad * 8]);
        bf16x8 b0 = *(const bf16x8*)(&Bs[wn + r][quad * 8]);
        bf16x8 b1 = *(const bf16x8*)(&Bs[wn + 16 + r][quad * 8]);
        acc[0][0] = __builtin_amdgcn_mfma_f32_16x16x32_bf16(a0, b0, acc[0][0], 0, 0, 0);
        acc[0][1] = __builtin_amdgcn_mfma_f32_16x16x32_bf16(a0, b1, acc[0][1], 0, 0, 0);
        acc[1][0] = __builtin_amdgcn_mfma_f32_16x16x32_bf16(a1, b0, acc[1][0], 0, 0, 0);
        acc[1][1] = __builtin_amdgcn_mfma_f32_16x16x32_bf16(a1, b1, acc[1][1], 0, 0, 0);
    }
    #pragma unroll
    for (int i = 0; i < 2; ++i)
        #pragma unroll
        for (int jn = 0; jn < 2; ++jn)
            #pragma unroll
            for (int t = 0; t < 4; ++t) {
                int grow = row0 + wm + i * 16 + quad * 4 + t;
                int gcol = col0 + wn + jn * 16 + r;
                if (grow >= M) continue;
                float v = acc[i][jn][t];
                size_t off = (size_t)grow * N + gcol;
                if (EPI == 0) {
                    ((u16*)Cout)[off] = f2bf(v);
                } else if (EPI == 2) {
                    Rf[off] += v + ldf(bias, gcol, isf32);
                } else {
                    ((float*)Cout)[off] = v + ldf(bias, gcol, isf32) + Rf[off];
                }
            }
}

// ============ FALLBACK: round-4 geglu ============
__global__ __launch_bounds__(256) void k_gemm_geglu(const u16* __restrict__ A, const void* __restrict__ B,
                                                    const void* __restrict__ bias, u16* __restrict__ Out,
                                                    int M, int Nout, int K, int ldb,
                                                    const int* __restrict__ flagp) {
    int isf32 = *flagp;
    __shared__ u16 As[64][40];
    __shared__ u16 Bs[64][40];
    int tid = threadIdx.x;
    int row0 = blockIdx.x * 64, col0 = blockIdx.y * 64;
    int wave = tid >> 6, lane = tid & 63;
    int wm = (wave >> 1) * 32, wn = (wave & 1) * 32;
    int quad = lane >> 4, r = lane & 15;
    int arow = tid >> 2, akk = (tid & 3) * 8;
    int bnl = tid & 63, bkk = (tid >> 6) * 8;
    int garow = row0 + arow;
    f32x4 acc[2][2][2] = {};
    for (int p = 0; p < 2; ++p) {
        for (int k0 = 0; k0 < K; k0 += 32) {
            uint4 aval = {0u, 0u, 0u, 0u};
            if (garow < M) aval = *(const uint4*)(A + (size_t)garow * K + k0 + akk);
            u16 btmp[8];
            #pragma unroll
            for (int j = 0; j < 8; ++j)
                btmp[j] = ldbf(B, (size_t)(k0 + bkk + j) * ldb + p * Nout + col0 + bnl, isf32);
            __syncthreads();
            *(uint4*)(&As[arow][akk]) = aval;
            *(uint4*)(&Bs[bnl][bkk]) = *(uint4*)btmp;
            __syncthreads();
            bf16x8 a0 = *(const bf16x8*)(&As[wm + r][quad * 8]);
            bf16x8 a1 = *(const bf16x8*)(&As[wm + 16 + r][quad * 8]);
            bf16x8 b0 = *(const bf16x8*)(&Bs[wn + r][quad * 8]);
            bf16x8 b1 = *(const bf16x8*)(&Bs[wn + 16 + r][quad * 8]);
            acc[p][0][0] = __builtin_amdgcn_mfma_f32_16x16x32_bf16(a0, b0, acc[p][0][0], 0, 0, 0);
            acc[p][0][1] = __builtin_amdgcn_mfma_f32_16x16x32_bf16(a0, b1, acc[p][0][1], 0, 0, 0);
            acc[p][1][0] = __builtin_amdgcn_mfma_f32_16x16x32_bf16(a1, b0, acc[p][1][0], 0, 0, 0);
            acc[p][1][1] = __builtin_amdgcn_mfma_f32_16x16x32_bf16(a1, b1, acc[p][1][1], 0, 0, 0);
        }
    }
    #pragma unroll
    for (int i = 0; i < 2; ++i)
        #pragma unroll
        for (int jn = 0; jn < 2; ++jn)
            #pragma unroll
            for (int t = 0; t < 4; ++t) {
                int grow = row0 + wm + i * 16 + quad * 4 + t;
                int gcol = col0 + wn + jn * 16 + r;
                if (grow >= M) continue;
                float a = acc[0][i][jn][t] + ldf(bias, gcol, isf32);
                float u = acc[1][i][jn][t] + ldf(bias, Nout + gcol, isf32);
                float th = tanhf(0.7978845608f * (u + 0.044715f * u * u * u));
                float gl = 0.5f * u * (1.f + th);
                Out[(size_t)grow * Nout + gcol] = f2bf(a * gl);
            }
}

// ---------------- MFMA flash attention, KVBLK=64, SWAPPED QK^T (kv in-lane softmax) ----------------
// s[g] = mfma(K_frag, Q_frag): first operand's rows -> D rows (verified via k_gemm_t's
// C-write mapping). Lane (r,quad) holds S[kv = kv0+g*16+quad*4+t][q = q0+r]: the kv axis
// is IN-LANE (16 vals) -> row reduction = in-lane tree + shfl_xor(16) + shfl_xor(32)
// (4 shfls/tile vs 32 before). m/l are per-lane scalars (q=r); alpha/l redistributed to
// accO rows (q=quad*4+t) via 4 __shfl broadcasts. P stored Sp[q=r][kv], PV unchanged.
__global__ __launch_bounds__(256) void k_attn_flash(const u16* __restrict__ Q, const u16* __restrict__ K,
                                                    const u16* __restrict__ V, u16* __restrict__ O,
                                                    int N, int Mkv, int H, int ldq, int ldkv, int ldo) {
    __shared__ u16 KT[64][72];       // K rows as-is: [kv][d]
    __shared__ u16 VT[64][72];       // V transposed: [d][kv]
    __shared__ u16 Sp[4][16][72];    // P per wave: [q][kv0..63]
    const float SC = 0.18033688f;    // 0.125 * log2(e)
    int nt = N / 64;
    int qt = blockIdx.x % nt;
    int bh = blockIdx.x / nt;
    int h = bh % H, b = bh / H;
    int tid = threadIdx.x, wave = tid >> 6, lane = tid & 63;
    int quad = lane >> 4, r = lane & 15;
    int q0 = qt * 64 + wave * 16;

    const u16* qbase = Q + ((size_t)(b * N + q0 + r)) * ldq + h * 64;
    bf16x8 aq0 = *(const bf16x8*)(qbase + quad * 8);
    bf16x8 aq1 = *(const bf16x8*)(qbase + 32 + quad * 8);

    f32x4 accO[4] = {};              // accO[g][t] = out[q=quad*4+t][d=g*16+r]
    float m_i = -1e30f, l_i = 0.f;   // per-lane softmax state for q row = r

    // staging: 256 threads cover 64 rows x 64 cols
    int srow = tid >> 2;
    int scol = (tid & 3) * 8;

    for (int kv0 = 0; kv0 < Mkv; kv0 += 64) {
        int krow = min(kv0 + srow, Mkv - 1);
        const u16* kp = K + ((size_t)(b * Mkv + krow)) * ldkv + h * 64;
        const u16* vp = V + ((size_t)(b * Mkv + krow)) * ldkv + h * 64;
        uint4 ka = *(const uint4*)(kp + scol);
        uint4 kb = *(const uint4*)(kp + scol + 32);
        uint4 va = *(const uint4*)(vp + scol);
        uint4 vb = *(const uint4*)(vp + scol + 32);

        __syncthreads();             // prior tile's LDS reads complete
        *(uint4*)(&KT[srow][scol]) = ka;
        *(uint4*)(&KT[srow][scol + 32]) = kb;
        u16 tmp[16];
        *(uint4*)tmp = va; *(uint4*)(tmp + 8) = vb;
        #pragma unroll
        for (int j = 0; j < 8; ++j) {
            VT[scol + j][srow] = tmp[j];
            VT[scol + 32 + j][srow] = tmp[8 + j];
        }
        __syncthreads();

        // K frags (A operand): rows g*16 + r, d halves
        bf16x8 bk[4][2];
        #pragma unroll
        for (int g = 0; g < 4; ++g) {
            bk[g][0] = *(const bf16x8*)(&KT[g * 16 + r][quad * 8]);
            bk[g][1] = *(const bf16x8*)(&KT[g * 16 + r][32 + quad * 8]);
        }
        // SWAPPED: D[kv][q]; lane holds kv = g*16+quad*4+t, q = r
        f32x4 s[4] = {};
        #pragma unroll
        for (int g = 0; g < 4; ++g) {
            s[g] = __builtin_amdgcn_mfma_f32_16x16x32_bf16(bk[g][0], aq0, s[g], 0, 0, 0);
            s[g] = __builtin_amdgcn_mfma_f32_16x16x32_bf16(bk[g][1], aq1, s[g], 0, 0, 0);
        }

        float v[4][4];
        float vmax = -1e30f;
        #pragma unroll
        for (int g = 0; g < 4; ++g)
            #pragma unroll
            for (int t = 0; t < 4; ++t) {
                int kvi = kv0 + g * 16 + quad * 4 + t;
                v[g][t] = (kvi < Mkv) ? s[g][t] * SC : -1e30f;
                vmax = fmaxf(vmax, v[g][t]);
            }
        vmax = fmaxf(vmax, __shfl_xor(vmax, 16));
        vmax = fmaxf(vmax, __shfl_xor(vmax, 32));
        float mn = fmaxf(m_i, vmax);
        float alpha = exp2f(m_i - mn);
        float ps = 0.f;
        #pragma unroll
        for (int g = 0; g < 4; ++g)
            #pragma unroll
            for (int t = 0; t < 4; ++t) {
                v[g][t] = exp2f(v[g][t] - mn);   // masked entries -> 0
                ps += v[g][t];
            }
        ps += __shfl_xor(ps, 16);
        ps += __shfl_xor(ps, 32);
        l_i = l_i * alpha + ps;
        m_i = mn;
        // rescale accO rows with their own alpha (row q = quad*4+t lives in lane q of 0..15)
        #pragma unroll
        for (int t = 0; t < 4; ++t) {
            float art = __shfl(alpha, quad * 4 + t);
            accO[0][t] *= art; accO[1][t] *= art; accO[2][t] *= art; accO[3][t] *= art;
        }
        // store P: Sp[q=r][kv]
        #pragma unroll
        for (int g = 0; g < 4; ++g)
            #pragma unroll
            for (int t = 0; t < 4; ++t)
                Sp[wave][r][g * 16 + quad * 4 + t] = f2bf(v[g][t]);

        // PV: A = P rows (q), B = V^T rows (d); kv halves 0..31 / 32..63
        bf16x8 ap0 = *(const bf16x8*)(&Sp[wave][r][quad * 8]);
        bf16x8 ap1 = *(const bf16x8*)(&Sp[wave][r][32 + quad * 8]);
        #pragma unroll
        for (int g = 0; g < 4; ++g) {
            bf16x8 bv0 = *(const bf16x8*)(&VT[g * 16 + r][quad * 8]);
            bf16x8 bv1 = *(const bf16x8*)(&VT[g * 16 + r][32 + quad * 8]);
            accO[g] = __builtin_amdgcn_mfma_f32_16x16x32_bf16(ap0, bv0, accO[g], 0, 0, 0);
            accO[g] = __builtin_amdgcn_mfma_f32_16x16x32_bf16(ap1, bv1, accO[g], 0, 0, 0);
        }
    }

    u16* ob = O + ((size_t)(b * N + q0)) * ldo + h * 64;
    #pragma unroll
    for (int t = 0; t < 4; ++t) {
        float lr = __shfl(l_i, quad * 4 + t);
        float inv = 1.f / lr;
        #pragma unroll
        for (int g = 0; g < 4; ++g)
            ob[(size_t)(quad * 4 + t) * ldo + g * 16 + r] = f2bf(accO[g][t] * inv);
    }
}

extern "C" void kernel_launch(void* const* d_in, const int* in_sizes, int n_in,
                              void* d_out, int out_size, void* d_ws, size_t ws_size,
                              hipStream_t stream) {
    const void* x    = d_in[0];
    const void* ctx  = d_in[1];
    const void* g1   = d_in[2];
    const void* be1  = d_in[3];
    const void* wq1  = d_in[4];
    const void* wk1  = d_in[5];
    const void* wv1  = d_in[6];
    const void* wo1  = d_in[7];
    const void* bo1  = d_in[8];
    const void* g2   = d_in[9];
    const void* be2  = d_in[10];
    const void* wq2  = d_in[11];
    const void* wk2  = d_in[12];
    const void* wv2  = d_in[13];
    const void* wo2  = d_in[14];
    const void* bo2  = d_in[15];
    const void* g3   = d_in[16];
    const void* be3  = d_in[17];
    const void* wff1 = d_in[18];
    const void* bff1 = d_in[19];
    const void* wff2 = d_in[20];
    const void* bff2 = d_in[21];

    const int BT = 4096, D = 1280;
    dim3 blk(256);
    char* ws = (char*)d_ws;

    const size_t NEED_FAST = 117393664;
    if (ws_size >= NEED_FAST) {
        // ---------- fast path ----------
        int*   flag   = (int*)(ws);
        u16* lnout    = (u16*)(ws + 256);            // 4096x1280 bf16
        u16* qkv      = (u16*)(ws + 10486016);       // 4096x3840 bf16 (region R)
        u16* attnout  = (u16*)(ws + 10486016 + 31457280);
        u16* gbuf     = (u16*)(ws + 10486016);       // 4096x5120 bf16, aliases qkv+attnout
        u16* ctxb     = (u16*)(ws + 52429056);       // 308x768 bf16
        u16* kv2      = (u16*)(ws + 52902144);       // 308x2560 bf16
        u16* wqkv1t   = (u16*)(ws + 54479104);       // [3840][1280]
        u16* wo1t     = (u16*)(ws + 64309504);       // [1280][1280]
        u16* wq2t     = (u16*)(ws + 67586304);
        u16* wkv2t    = (u16*)(ws + 70863104);       // [2560][768]
        u16* wo2t     = (u16*)(ws + 74795264);
        u16* wff1t    = (u16*)(ws + 78072064);       // [10240][1280]
        u16* wff2t    = (u16*)(ws + 104286464);      // [1280][5120]
        float* pff2   = (float*)(ws + 54479104);     // FF2 split-K partial (21 MB); weights dead there
        float* pWO    = (float*)(ws + 10486016);     // WO1/WO2 split-K partial (21 MB) in dead qkv region
        float* xres   = (float*)d_out;               // residual lives in the fp32 output

        k_detect<<<dim3(1), blk, 0, stream>>>((const u16*)x, flag);
        k_b2f<<<dim3((BT * D + 255) / 256), blk, 0, stream>>>(x, xres, BT * D, flag);
        // weight transposes (batched: 10 -> 5 launches)
        k_transpose3<<<dim3(40, 40, 3), blk, 0, stream>>>(wq1, wk1, wv1,
                                                          wqkv1t, wqkv1t + 1280 * 1280,
                                                          wqkv1t + 2 * 1280 * 1280, 1280, 1280, flag);
        k_transpose3<<<dim3(40, 40, 3), blk, 0, stream>>>(wo1, wq2, wo2,
                                                          wo1t, wq2t, wo2t, 1280, 1280, flag);
        k_transpose3<<<dim3(24, 40, 2), blk, 0, stream>>>(wk2, wv2, wv2,
                                                          wkv2t, wkv2t + 1280 * 768,
                                                          wkv2t + 1280 * 768, 768, 1280, flag);
        k_transpose<<<dim3(40, 320), blk, 0, stream>>>(wff1, wff1t, 1280, 10240, flag);
        k_transpose<<<dim3(160, 40), blk, 0, stream>>>(wff2, wff2t, 5120, 1280, flag);
        k_cvt<<<dim3((308 * 768 + 255) / 256), blk, 0, stream>>>(ctx, ctxb, 308 * 768, flag);
        // --- self attention ---
        k_layernorm<<<dim3(BT), blk, 0, stream>>>(xres, nullptr, g1, be1, lnout, D, flag);
        k_gemm8<0><<<dim3(16, 15), dim3(512), 0, stream>>>(lnout, wqkv1t, qkv, nullptr, BT, 3840, D, flag);
        k_attn_flash<<<dim3(16 * 80), blk, 0, stream>>>(qkv, qkv + 1280, qkv + 2560, attnout,
                                                        1024, 1024, 20, 3840, 3840, 1280);
        // WO1: split-K=2; kz1 partial -> pWO (qkv region now dead); folded by LN2
        k_gemm_t<2><<<dim3(32, 10, 2), blk, 0, stream>>>(attnout, wo1t, pWO, xres, bo1, BT, D, D, flag);
        // --- cross attention ---
        k_layernorm<<<dim3(BT), blk, 0, stream>>>(xres, pWO, g2, be2, lnout, D, flag);
        k_gemm_t<0><<<dim3(32, 10), blk, 0, stream>>>(lnout, wq2t, qkv, nullptr, nullptr, BT, D, D, flag);
        k_gemm_t<0><<<dim3(3, 20), blk, 0, stream>>>(ctxb, wkv2t, kv2, nullptr, nullptr, 308, 2560, 768, flag);
        k_attn_flash<<<dim3(16 * 80), blk, 0, stream>>>(qkv, kv2, kv2 + 1280, attnout,
                                                        1024, 77, 20, 1280, 2560, 1280);
        // WO2: split-K=2; kz1 partial -> pWO (qkv dead again); folded by LN3
        k_gemm_t<2><<<dim3(32, 10, 2), blk, 0, stream>>>(attnout, wo2t, pWO, xres, bo2, BT, D, D, flag);
        // --- GEGLU FF ---
        k_layernorm<<<dim3(BT), blk, 0, stream>>>(xres, pWO, g3, be3, lnout, D, flag);
        k_gemm8<1><<<dim3(16, 40), dim3(512), 0, stream>>>(lnout, wff1t, gbuf, bff1, BT, 10240, D, flag);
        // FF2: split-K=2; kz1 partial -> pff2; fold with k_addp (final output, no following LN)
        k_gemm_t<2><<<dim3(32, 10, 2), blk, 0, stream>>>(gbuf, wff2t, pff2, xres, bff2, BT, D, 5120, flag);
        k_addp<<<dim3(2048), blk, 0, stream>>>(xres, pff2, BT * D / 4);
    } else {
        // ---------- fallback: round-4 path (known-good, ~75 MB ws) ----------
        int*   flag    = (int*)(ws);
        float* xres    = (float*)(ws + 256);
        u16* lnout     = (u16*)(ws + 20971776);
        u16* q         = (u16*)(ws + 31457536);
        u16* kbuf      = (u16*)(ws + 41943296);
        u16* vbuf      = (u16*)(ws + 52429056);
        u16* attnout   = (u16*)(ws + 62914816);
        u16* k2        = (u16*)(ws + 73400576);
        u16* v2        = (u16*)(ws + 74189056);
        u16* gbuf      = (u16*)(ws + 31457536);

        dim3 g_gemm(64, 20);
        dim3 g_kv(5, 20);
        dim3 g_attn(16 * 80);

        k_detect<<<dim3(1), blk, 0, stream>>>((const u16*)x, flag);
        k_b2f<<<dim3((BT * D + 255) / 256), blk, 0, stream>>>(x, xres, BT * D, flag);
        k_layernorm<<<dim3(BT), blk, 0, stream>>>(xres, nullptr, g1, be1, lnout, D, flag);
        k_gemm<0, false><<<g_gemm, blk, 0, stream>>>(lnout, wq1, q, nullptr, nullptr, BT, D, D, flag);
        k_gemm<0, false><<<g_gemm, blk, 0, stream>>>(lnout, wk1, kbuf, nullptr, nullptr, BT, D, D, flag);
        k_gemm<0, false><<<g_gemm, blk, 0, stream>>>(lnout, wv1, vbuf, nullptr, nullptr, BT, D, D, flag);
        k_attn_flash<<<g_attn, blk, 0, stream>>>(q, kbuf, vbuf, attnout, 1024, 1024, 20, 1280, 1280, 1280);
        k_gemm<2, false><<<g_gemm, blk, 0, stream>>>(attnout, wo1, nullptr, xres, bo1, BT, D, D, flag);
        k_layernorm<<<dim3(BT), blk, 0, stream>>>(xres, nullptr, g2, be2, lnout, D, flag);
        k_gemm<0, false><<<g_gemm, blk, 0, stream>>>(lnout, wq2, q, nullptr, nullptr, BT, D, D, flag);
        k_gemm<0, true><<<g_kv, blk, 0, stream>>>(ctx, wk2, k2, nullptr, nullptr, 308, D, 768, flag);
        k_gemm<0, true><<<g_kv, blk, 0, stream>>>(ctx, wv2, v2, nullptr, nullptr, 308, D, 768, flag);
        k_attn_flash<<<g_attn, blk, 0, stream>>>(q, k2, v2, attnout, 1024, 77, 20, 1280, 1280, 1280);
        k_gemm<2, false><<<g_gemm, blk, 0, stream>>>(attnout, wo2, nullptr, xres, bo2, BT, D, D, flag);
        k_layernorm<<<dim3(BT), blk, 0, stream>>>(xres, nullptr, g3, be3, lnout, D, flag);
        k_gemm_geglu<<<dim3(64, 80), blk, 0, stream>>>(lnout, wff1, bff1, gbuf, BT, 5120, D, 10240, flag);
        k_gemm<3, false><<<g_gemm, blk, 0, stream>>>(gbuf, wff2, d_out, xres, bff2, BT, D, 5120, flag);
    }
}